// Round 2
// baseline (2737.775 us; speedup 1.0000x reference)
//
#include <hip/hip_runtime.h>
#include <math.h>

#define N_NODE 200
#define RING   512
#define NSTEP  500
#define TB     16
#define NB     32          // ceil(500/16)
#define NWG    8
#define NTHR   512
#define JSL    25          // j-rows per WG slice
#define NEARCAP 32         // near band is now d < 32
#define MDEP   36          // Mrec depth (>= 33, mod-36 slots)

// ---- ws layout (float element offsets) ----
#define FPBUF   (NWG * N_NODE * TB)   // 25600 floats per parity buffer
#define OFF_FP  0                     // [2][NWG][200][16] far partials, parity by (block&1)
#define OFF_BAR (2 * FPBUF)           // [64] int barrier counters
#define WS_NEED ((size_t)(2 * FPBUF + 64) * 4)

// ---- static LDS layout (byte offsets into smem[]) ----
#define SM_RED   0         // double[8]
#define SM_MREC  64        // float[36*200]  recent M history (mod-36 slots)
#define SM_NJD   28864     // u32 [200*32]   near (j | d<<16), d<32
#define SM_NW    54464     // float[200*32]  near weights
#define SM_NCNT  80064     // int[200]
#define SM_LED   80864     // float[2][16][200] double-buffered far sums
#define SM_RING  106464    // float[25*512]  own j-slice M ring
#define SM_TOTAL 157664
// epilogue overlays (after main loop; do not touch SM_RING until hEb flushed)
#define SM_LMT   64        // float[64*200]
#define SM_DIFF  51264     // float[200*50]

__device__ __forceinline__ float sigm(float x) {
    return 5.0f / (1.0f + expf(0.56f * (6.0f - x)));
}
__device__ __forceinline__ float satf(float x) {
    return 1000.0f * tanhf(x / 1000.0f);
}

__global__ void zero_bar(int* bar) {
    if (threadIdx.x < 64) bar[threadIdx.x] = 0;
}

__global__ __launch_bounds__(NTHR, 1)
void jansen_pipe(const float* __restrict__ inp, const float* __restrict__ noise_in,
                 const float* __restrict__ hx,  const float* __restrict__ hE,
                 const float* __restrict__ sc,  const float* __restrict__ wbb,
                 const float* __restrict__ lm,  const int*   __restrict__ delays,
                 float* __restrict__ out, float* __restrict__ ws)
{
    __shared__ char smem[SM_TOTAL];
    double*   red  = (double*)(smem + SM_RED);
    float*    Mrec = (float*)(smem + SM_MREC);
    unsigned* nJD  = (unsigned*)(smem + SM_NJD);
    float*    nW   = (float*)(smem + SM_NW);
    int*      nCnt = (int*)(smem + SM_NCNT);
    float*    LEdS = (float*)(smem + SM_LED);
    float*    ringS= (float*)(smem + SM_RING);

    const int  tid   = threadIdx.x;
    const int  wg    = blockIdx.x;
    const bool lower = tid < 256;
    const int  i     = lower ? tid : tid - 256;   // node id (active if < 200)
    const int  jlo   = wg * JSL;

    float* fp  = ws + OFF_FP;
    int*   bar = (int*)(ws + OFF_BAR);

    // ---- pass A: Frobenius norm of wl (redundant per WG) ----
    double ssq = 0.0;
    for (int q = tid; q < N_NODE * N_NODE; q += NTHR) {
        int j = q / N_NODE, ii = q - j * N_NODE;
        float w1 = expf(wbb[ii * N_NODE + j]) * sc[ii * N_NODE + j];
        float w2 = expf(wbb[j * N_NODE + ii]) * sc[j * N_NODE + ii];
        float wl = log1pf(0.5f * (w1 + w2));
        ssq += (double)wl * (double)wl;
    }
    #pragma unroll
    for (int off = 32; off > 0; off >>= 1) ssq += __shfl_down(ssq, off, 64);
    if ((tid & 63) == 0) red[tid >> 6] = ssq;

    // ---- ring init: slot (t mod 512); history M[-1-dd] = hE[j][dd] at slot 511-dd ----
    for (int p = tid; p < JSL * RING; p += NTHR) {
        int jl = p >> 9, x = p & 511;
        int dd = 511 - x;
        ringS[p] = (dd < 500) ? hE[(jlo + jl) * 500 + dd] : 0.0f;
    }
    // ---- Mrec init: M[-q] at slot (36-q), q=1..32 -> slot s in [4,35]: hE[j][35-s] ----
    for (int p = tid; p < MDEP * N_NODE; p += NTHR) {
        int s = p / N_NODE, j = p - s * N_NODE;
        Mrec[p] = (s >= 4) ? hE[j * 500 + (35 - s)] : 0.0f;
    }
    __syncthreads();
    if (tid == 0) {
        double s = 0.0;
        #pragma unroll
        for (int r = 0; r < 8; ++r) s += red[r];
        red[0] = 1.0 / sqrt(s);
    }
    __syncthreads();
    const float inv = (float)red[0];

    // ---- pass B ----
    float rowsum = 0.0f;
    float M = 0, E = 0, I = 0, Mvv = 0, Evv = 0, Ivv = 0;
    float wreg[JSL];
    int   ereg[JSL];
    #pragma unroll
    for (int jl = 0; jl < JSL; ++jl) { wreg[jl] = 0.0f; ereg[jl] = 0; }
    if (lower && i < N_NODE) {
        // near list (d < 32, all j) + rowsum + state
        int cnt = 0;
        for (int j = 0; j < N_NODE; ++j) {
            float w1 = expf(wbb[i * N_NODE + j]) * sc[i * N_NODE + j];
            float w2 = expf(wbb[j * N_NODE + i]) * sc[j * N_NODE + i];
            float w  = log1pf(0.5f * (w1 + w2)) * inv;
            int d = delays[j * N_NODE + i];
            rowsum += w;
            if (d < NEARCAP && cnt < NEARCAP) {
                nJD[i * NEARCAP + cnt] = (unsigned)(j | (d << 16));
                nW [i * NEARCAP + cnt] = w;
                ++cnt;
            }
        }
        nCnt[i] = cnt;
        M   = hx[i * 6 + 0]; E   = hx[i * 6 + 1]; I   = hx[i * 6 + 2];
        Mvv = hx[i * 6 + 3]; Evv = hx[i * 6 + 4]; Ivv = hx[i * 6 + 5];
    }
    if (!lower && i < N_NODE) {
        // own-slice far weights -> registers (d >= 32 only)
        #pragma unroll
        for (int jl = 0; jl < JSL; ++jl) {
            int j = jlo + jl;
            float w1 = expf(wbb[i * N_NODE + j]) * sc[i * N_NODE + j];
            float w2 = expf(wbb[j * N_NODE + i]) * sc[j * N_NODE + i];
            float w  = log1pf(0.5f * (w1 + w2)) * inv;
            int d = delays[j * N_NODE + i];
            wreg[jl] = (d < NEARCAP) ? 0.0f : w;
            ereg[jl] = 511 - d;
        }
    }
    __syncthreads();

    // ---- prologue: far(0) + gather -> LEdS[0]; lower: u/n regs for block 0 ----
    float uR[16], nR[16], uRn[16], nRn[16];
    if (lower && i < N_NODE) {
        #pragma unroll
        for (int k = 0; k < 16; ++k) {
            int bb = k / 10, h = k - 10 * bb;
            uR[k] = inp     [i * 500 + h * 50 + bb];
            nR[k] = noise_in[i * 500 + h * 50 + bb];
        }
    }
    if (!lower && i < N_NODE) {
        float ac0[16];
        #pragma unroll
        for (int k = 0; k < 16; ++k) ac0[k] = 0.0f;
        #pragma unroll
        for (int jl = 0; jl < JSL; ++jl) {
            float w  = wreg[jl];
            int   p0 = ereg[jl] & 511;
            const float* rb = ringS + (jl << 9);
            #pragma unroll
            for (int k = 0; k < 16; ++k)
                ac0[k] = fmaf(w, rb[(p0 + k) & 511], ac0[k]);
        }
        float4* fpw = (float4*)(fp + 0 * FPBUF + wg * (N_NODE * TB) + i * TB);
        fpw[0] = make_float4(ac0[ 0], ac0[ 1], ac0[ 2], ac0[ 3]);
        fpw[1] = make_float4(ac0[ 4], ac0[ 5], ac0[ 6], ac0[ 7]);
        fpw[2] = make_float4(ac0[ 8], ac0[ 9], ac0[10], ac0[11]);
        fpw[3] = make_float4(ac0[12], ac0[13], ac0[14], ac0[15]);
        __threadfence();
    }
    __syncthreads();
    if (tid == 256) {
        __hip_atomic_fetch_add(&bar[32], 1, __ATOMIC_ACQ_REL, __HIP_MEMORY_SCOPE_AGENT);
        while (__hip_atomic_load(&bar[32], __ATOMIC_ACQUIRE, __HIP_MEMORY_SCOPE_AGENT) < NWG)
            __builtin_amdgcn_s_sleep(2);
        __threadfence();
    }
    __syncthreads();
    if (!lower && i < N_NODE) {
        #pragma unroll
        for (int c = 0; c < 4; ++c) {
            float sx = 0, sy = 0, sz = 0, sw = 0;
            #pragma unroll
            for (int g = 0; g < NWG; ++g) {
                float4 q = *(const float4*)(fp + 0 * FPBUF + g * (N_NODE * TB) + i * TB + c * 4);
                sx += q.x; sy += q.y; sz += q.z; sw += q.w;
            }
            LEdS[0 * 3200 + (c * 4 + 0) * N_NODE + i] = sx;
            LEdS[0 * 3200 + (c * 4 + 1) * N_NODE + i] = sy;
            LEdS[0 * 3200 + (c * 4 + 2) * N_NODE + i] = sz;
            LEdS[0 * 3200 + (c * 4 + 3) * N_NODE + i] = sw;
        }
    }
    __syncthreads();

    // ---------------- main loop: inner(b) || far-pipeline(b+1) ----------------
    for (int b = 0; b < NB; ++b) {
        const int t0   = b * TB;
        const int led  = (b & 1) * 3200;
        const int ledn = ((b + 1) & 1) * 3200;
        float* fpn = fp + ((b + 1) & 1) * FPBUF;
        const int t0m = t0 % MDEP;
        const bool doFar = (!lower) && (i < N_NODE) && (b < NB - 1);
        const bool doSim = lower && (i < N_NODE);
        const int t1 = t0 + TB;            // far target block start

        float ac[16];
        float4 g0, g1, g2, g3, g4, g5, g6, g7;
        float4 h0, h1, h2, h3, h4, h5, h6, h7;
        // far chunk schedule over steps 0..8
        static constexpr int FS[10] = {0, 3, 6, 9, 12, 15, 18, 21, 23, 25};

        #pragma unroll
        for (int k = 0; k < 16; ++k) {
            const int t = t0 + k;
            if (doSim) {
                if (t < NSTEP) {
                    float LEd = LEdS[led + k * N_NODE + i];
                    int cnt = nCnt[i];
                    int s36 = t0m + k; if (s36 >= MDEP) s36 -= MDEP;   // t mod 36
                    for (int n = 0; n < cnt; ++n) {
                        unsigned jd = nJD[i * NEARCAP + n];
                        int j = jd & 0xffff, d = (int)(jd >> 16);
                        int r = s36 - 1 - d; if (r < 0) r += MDEP;
                        LEd = fmaf(nW[i * NEARCAP + n], Mrec[r * N_NODE + j], LEd);
                    }
                    float u  = uR[k];
                    float nz = nR[k];
                    float rM = sigm(E - I);
                    float rE = 250.0f * nz + 1000.01f * (LEd - rowsum * E) + 108.01f * sigm(135.01f * M);
                    float rI = 33.76f * sigm(33.76f * M);
                    float ddM = M + 1e-4f * Mvv;
                    float ddE = E + 1e-4f * Evv;
                    float ddI = I + 1e-4f * Ivv;
                    float uu  = u + 500.0f * tanhf(rM / 500.0f);
                    float ddMv = Mvv + 1e-4f * (328.25f * uu - 202.0f * Mvv - 10201.0f * M);
                    float uE  = 500.0f * tanhf(rE / 500.0f);
                    float ddEv = Evv + 1e-4f * (328.25f * uE - 202.0f * Evv - 10201.0f * E);
                    float uI  = 500.0f * tanhf(rI / 500.0f);
                    float ddIv = Ivv + 1e-4f * (1122.0f * uI - 102.0f * Ivv - 2601.0f * I);
                    M   = satf(ddM);  E   = satf(ddE);  I   = satf(ddI);
                    Mvv = satf(ddMv); Evv = satf(ddEv); Ivv = satf(ddIv);
                    Mrec[s36 * N_NODE + i] = M;
                    if (i >= jlo && i < jlo + JSL) {
                        ringS[((i - jlo) << 9) | (t & 511)] = M;
                    }
                    if (wg == 0) {
                        int bb = t / 10, h = t - 10 * bb;
                        if (h == 9) {
                            out[ 4400 + i * 50 + bb] = E;
                            out[14400 + i * 50 + bb] = I;
                            out[24400 + i * 50 + bb] = M;
                            out[34400 + i * 50 + bb] = Evv;
                            out[44400 + i * 50 + bb] = Ivv;
                            out[54400 + i * 50 + bb] = Mvv;
                        }
                    }
                }
                if (k == 8) {   // prefetch u/n for block b+1 into regs
                    #pragma unroll
                    for (int kk = 0; kk < 16; ++kk) {
                        int t2 = t0 + TB + kk;
                        if (t2 < NSTEP) {
                            int bb = t2 / 10, h = t2 - 10 * bb;
                            uRn[kk] = inp     [i * 500 + h * 50 + bb];
                            nRn[kk] = noise_in[i * 500 + h * 50 + bb];
                        }
                    }
                }
                if (k == 15) {
                    #pragma unroll
                    for (int kk = 0; kk < 16; ++kk) { uR[kk] = uRn[kk]; nR[kk] = nRn[kk]; }
                }
            } else if (!lower) {
                if (doFar) {
                    if (k == 0) {
                        #pragma unroll
                        for (int k2 = 0; k2 < 16; ++k2) ac[k2] = 0.0f;
                    }
                    if (k < 9) {   // far FMA chunks
                        #pragma unroll
                        for (int jl = FS[k]; jl < FS[k + 1]; ++jl) {
                            float w  = wreg[jl];
                            int   p0 = (t1 + ereg[jl]) & 511;
                            const float* rb = ringS + (jl << 9);
                            #pragma unroll
                            for (int k2 = 0; k2 < 16; ++k2)
                                ac[k2] = fmaf(w, rb[(p0 + k2) & 511], ac[k2]);
                        }
                    }
                    if (k == 9) {  // publish partials
                        float4* fpw = (float4*)(fpn + wg * (N_NODE * TB) + i * TB);
                        fpw[0] = make_float4(ac[ 0], ac[ 1], ac[ 2], ac[ 3]);
                        fpw[1] = make_float4(ac[ 4], ac[ 5], ac[ 6], ac[ 7]);
                        fpw[2] = make_float4(ac[ 8], ac[ 9], ac[10], ac[11]);
                        fpw[3] = make_float4(ac[12], ac[13], ac[14], ac[15]);
                        __threadfence();
                    }
                    if (k == 10 && tid == 256) {
                        __hip_atomic_fetch_add(&bar[b], 1, __ATOMIC_ACQ_REL, __HIP_MEMORY_SCOPE_AGENT);
                    }
                    if (k == 11 && tid == 256) {
                        while (__hip_atomic_load(&bar[b], __ATOMIC_ACQUIRE, __HIP_MEMORY_SCOPE_AGENT) < NWG)
                            __builtin_amdgcn_s_sleep(2);
                        __threadfence();
                    }
                    if (k == 12) {  // issue gather quads 0,1
                        const float* base = fpn + i * TB;
                        g0 = *(const float4*)(base + 0 * 3200 + 0);
                        g1 = *(const float4*)(base + 1 * 3200 + 0);
                        g2 = *(const float4*)(base + 2 * 3200 + 0);
                        g3 = *(const float4*)(base + 3 * 3200 + 0);
                        g4 = *(const float4*)(base + 4 * 3200 + 0);
                        g5 = *(const float4*)(base + 5 * 3200 + 0);
                        g6 = *(const float4*)(base + 6 * 3200 + 0);
                        g7 = *(const float4*)(base + 7 * 3200 + 0);
                        h0 = *(const float4*)(base + 0 * 3200 + 4);
                        h1 = *(const float4*)(base + 1 * 3200 + 4);
                        h2 = *(const float4*)(base + 2 * 3200 + 4);
                        h3 = *(const float4*)(base + 3 * 3200 + 4);
                        h4 = *(const float4*)(base + 4 * 3200 + 4);
                        h5 = *(const float4*)(base + 5 * 3200 + 4);
                        h6 = *(const float4*)(base + 6 * 3200 + 4);
                        h7 = *(const float4*)(base + 7 * 3200 + 4);
                    }
                    if (k == 13) {  // consume quads 0,1; issue quads 2,3
                        float sx, sy, sz, sw;
                        sx = g0.x + g1.x + g2.x + g3.x + g4.x + g5.x + g6.x + g7.x;
                        sy = g0.y + g1.y + g2.y + g3.y + g4.y + g5.y + g6.y + g7.y;
                        sz = g0.z + g1.z + g2.z + g3.z + g4.z + g5.z + g6.z + g7.z;
                        sw = g0.w + g1.w + g2.w + g3.w + g4.w + g5.w + g6.w + g7.w;
                        LEdS[ledn +  0 * N_NODE + i] = sx;
                        LEdS[ledn +  1 * N_NODE + i] = sy;
                        LEdS[ledn +  2 * N_NODE + i] = sz;
                        LEdS[ledn +  3 * N_NODE + i] = sw;
                        sx = h0.x + h1.x + h2.x + h3.x + h4.x + h5.x + h6.x + h7.x;
                        sy = h0.y + h1.y + h2.y + h3.y + h4.y + h5.y + h6.y + h7.y;
                        sz = h0.z + h1.z + h2.z + h3.z + h4.z + h5.z + h6.z + h7.z;
                        sw = h0.w + h1.w + h2.w + h3.w + h4.w + h5.w + h6.w + h7.w;
                        LEdS[ledn +  4 * N_NODE + i] = sx;
                        LEdS[ledn +  5 * N_NODE + i] = sy;
                        LEdS[ledn +  6 * N_NODE + i] = sz;
                        LEdS[ledn +  7 * N_NODE + i] = sw;
                        const float* base = fpn + i * TB;
                        g0 = *(const float4*)(base + 0 * 3200 +  8);
                        g1 = *(const float4*)(base + 1 * 3200 +  8);
                        g2 = *(const float4*)(base + 2 * 3200 +  8);
                        g3 = *(const float4*)(base + 3 * 3200 +  8);
                        g4 = *(const float4*)(base + 4 * 3200 +  8);
                        g5 = *(const float4*)(base + 5 * 3200 +  8);
                        g6 = *(const float4*)(base + 6 * 3200 +  8);
                        g7 = *(const float4*)(base + 7 * 3200 +  8);
                        h0 = *(const float4*)(base + 0 * 3200 + 12);
                        h1 = *(const float4*)(base + 1 * 3200 + 12);
                        h2 = *(const float4*)(base + 2 * 3200 + 12);
                        h3 = *(const float4*)(base + 3 * 3200 + 12);
                        h4 = *(const float4*)(base + 4 * 3200 + 12);
                        h5 = *(const float4*)(base + 5 * 3200 + 12);
                        h6 = *(const float4*)(base + 6 * 3200 + 12);
                        h7 = *(const float4*)(base + 7 * 3200 + 12);
                    }
                    if (k == 14) {  // consume quads 2,3
                        float sx, sy, sz, sw;
                        sx = g0.x + g1.x + g2.x + g3.x + g4.x + g5.x + g6.x + g7.x;
                        sy = g0.y + g1.y + g2.y + g3.y + g4.y + g5.y + g6.y + g7.y;
                        sz = g0.z + g1.z + g2.z + g3.z + g4.z + g5.z + g6.z + g7.z;
                        sw = g0.w + g1.w + g2.w + g3.w + g4.w + g5.w + g6.w + g7.w;
                        LEdS[ledn +  8 * N_NODE + i] = sx;
                        LEdS[ledn +  9 * N_NODE + i] = sy;
                        LEdS[ledn + 10 * N_NODE + i] = sz;
                        LEdS[ledn + 11 * N_NODE + i] = sw;
                        sx = h0.x + h1.x + h2.x + h3.x + h4.x + h5.x + h6.x + h7.x;
                        sy = h0.y + h1.y + h2.y + h3.y + h4.y + h5.y + h6.y + h7.y;
                        sz = h0.z + h1.z + h2.z + h3.z + h4.z + h5.z + h6.z + h7.z;
                        sw = h0.w + h1.w + h2.w + h3.w + h4.w + h5.w + h6.w + h7.w;
                        LEdS[ledn + 12 * N_NODE + i] = sx;
                        LEdS[ledn + 13 * N_NODE + i] = sy;
                        LEdS[ledn + 14 * N_NODE + i] = sz;
                        LEdS[ledn + 15 * N_NODE + i] = sw;
                    }
                }
            }
            __syncthreads();
        }
    }

    // ---------------- epilogue ----------------
    // hEb slice: rows [jlo, jlo+JSL) from LDS ring
    for (int p = tid; p < JSL * 500; p += NTHR) {
        int jl = p / 500, dd = p - jl * 500;
        out[64400 + (jlo + jl) * 500 + dd] = ringS[(jl << 9) + ((499 - dd) & 511)];
    }
    if (wg != 0) return;

    if (lower && i < N_NODE) {
        out[3200 + i * 6 + 0] = M;
        out[3200 + i * 6 + 1] = E;
        out[3200 + i * 6 + 2] = I;
        out[3200 + i * 6 + 3] = Mvv;
        out[3200 + i * 6 + 4] = Evv;
        out[3200 + i * 6 + 5] = Ivv;
    }

    float* lmt  = (float*)(smem + SM_LMT);
    float* diff = (float*)(smem + SM_DIFF);
    __syncthreads();
    if (tid < 64) {
        float s = 0.0f;
        for (int n = 0; n < N_NODE; ++n) { float v = lm[tid * N_NODE + n]; s += v * v; }
        float ivn = 1.0f / sqrtf(s);
        for (int n = 0; n < N_NODE; ++n) lmt[tid * N_NODE + n] = lm[tid * N_NODE + n] * ivn;
    }
    __syncthreads();
    if (tid < N_NODE) {
        float s = 0.0f;
        for (int o = 0; o < 64; ++o) s += lmt[o * N_NODE + tid];
        s *= (1.0f / 64.0f);
        for (int o = 0; o < 64; ++o) lmt[o * N_NODE + tid] -= s;
    }
    __syncthreads();
    for (int p = tid; p < 10000; p += NTHR) diff[p] = out[4400 + p] - out[14400 + p];
    __syncthreads();
    for (int p = tid; p < 3200; p += NTHR) {
        int o = p / 50, bb = p - o * 50;
        float s = 0.0f;
        for (int n = 0; n < N_NODE; ++n)
            s = fmaf(lmt[o * N_NODE + n], diff[n * 50 + bb], s);
        out[p] = 5.0f * s - 2.0f;
    }
}

// ---------------- fallback: single-WG kernel ----------------
__global__ __launch_bounds__(1024, 1)
void jansen_main(const float* __restrict__ inp, const float* __restrict__ noise_in,
                 const float* __restrict__ hx,  const float* __restrict__ hE,
                 const float* __restrict__ sc,  const float* __restrict__ wbb,
                 const float* __restrict__ lm,  const int*   __restrict__ delays,
                 float* __restrict__ out, float* __restrict__ ws)
{
    const int tid = threadIdx.x;
    const int i   = tid & 255;
    const int c   = tid >> 8;

    float* ring = ws;
    float* lmt  = ws + N_NODE * RING;

    __shared__ double red[18];
    __shared__ float  part[4][N_NODE];
    __shared__ float  wn[N_NODE * N_NODE];

    double ssq = 0.0;
    for (int p = tid; p < N_NODE * N_NODE; p += 1024) {
        int r0 = p / N_NODE;
        int cc = p - r0 * N_NODE;
        float w1 = expf(wbb[p]) * sc[p];
        float w2 = expf(wbb[cc * N_NODE + r0]) * sc[cc * N_NODE + r0];
        float v  = log1pf(0.5f * (w1 + w2));
        wn[p] = v;
        ssq += (double)v * (double)v;
    }
    #pragma unroll
    for (int off = 32; off > 0; off >>= 1) ssq += __shfl_down(ssq, off, 64);
    if ((tid & 63) == 0) red[tid >> 6] = ssq;
    __syncthreads();
    if (tid == 0) {
        double s = 0.0;
        for (int k = 0; k < 16; ++k) s += red[k];
        red[16] = 1.0 / sqrt(s);
    }
    __syncthreads();
    const float inv_norm = (float)red[16];
    for (int p = tid; p < N_NODE * N_NODE; p += 1024) wn[p] *= inv_norm;

    for (int p = tid; p < N_NODE * 500; p += 1024) {
        int j = p / 500, dd = p - j * 500;
        ring[j * RING + (511 - dd)] = hE[p];
    }
    if (tid < 64) {
        float s = 0.0f;
        for (int n = 0; n < N_NODE; ++n) { float v = lm[tid * N_NODE + n]; s += v * v; }
        float inv = 1.0f / sqrtf(s);
        for (int n = 0; n < N_NODE; ++n) lmt[tid * N_NODE + n] = lm[tid * N_NODE + n] * inv;
    }
    __syncthreads();
    if (tid < N_NODE) {
        float s = 0.0f;
        for (int o = 0; o < 64; ++o) s += lmt[o * N_NODE + tid];
        s *= (1.0f / 64.0f);
        for (int o = 0; o < 64; ++o) lmt[o * N_NODE + tid] -= s;
    }

    unsigned int dpk[25];
    if (i < N_NODE) {
        #pragma unroll
        for (int r0 = 0; r0 < 25; ++r0) {
            int d0 = delays[(c * 50 + 2 * r0    ) * N_NODE + i];
            int d1 = delays[(c * 50 + 2 * r0 + 1) * N_NODE + i];
            unsigned e0 = (unsigned)((-1 - d0) & 511);
            unsigned e1 = (unsigned)((-1 - d1) & 511);
            dpk[r0] = e0 | (e1 << 16);
        }
    }

    float M = 0, E = 0, I = 0, Mvv = 0, Evv = 0, Ivv = 0, rowsum = 0;
    if (c == 0 && i < N_NODE) {
        M   = hx[i * 6 + 0]; E   = hx[i * 6 + 1]; I   = hx[i * 6 + 2];
        Mvv = hx[i * 6 + 3]; Evv = hx[i * 6 + 4]; Ivv = hx[i * 6 + 5];
    }
    __syncthreads();
    if (c == 0 && i < N_NODE) {
        float s = 0.0f;
        for (int j = 0; j < N_NODE; ++j) s += wn[j * N_NODE + i];
        rowsum = s;
    }

    for (int t = 0; t < NSTEP; ++t) {
        if (i < N_NODE) {
            float acc = 0.0f;
            const float* ringc = ring + c * 50 * RING;
            const float* wnc   = wn + c * 50 * N_NODE + i;
            #pragma unroll
            for (int r0 = 0; r0 < 50; ++r0) {
                unsigned e = (dpk[r0 >> 1] >> ((r0 & 1) << 4)) & 0xffffu;
                int pos = (int)(((unsigned)t + e) & 511u);
                acc = fmaf(wnc[r0 * N_NODE], ringc[r0 * RING + pos], acc);
            }
            part[c][i] = acc;
        }
        __syncthreads();
        if (c == 0 && i < N_NODE) {
            float LEd = part[0][i] + part[1][i] + part[2][i] + part[3][i];
            int b = t / 10, h = t - b * 10;
            float u  = inp     [i * 500 + h * 50 + b];
            float nz = noise_in[i * 500 + h * 50 + b];
            float rM = sigm(E - I);
            float rE = 250.0f * nz + 1000.01f * (LEd - rowsum * E) + 108.01f * sigm(135.01f * M);
            float rI = 33.76f * sigm(33.76f * M);
            float ddM = M + 1e-4f * Mvv;
            float ddE = E + 1e-4f * Evv;
            float ddI = I + 1e-4f * Ivv;
            float uu  = u + 500.0f * tanhf(rM / 500.0f);
            float ddMv = Mvv + 1e-4f * (328.25f * uu - 202.0f * Mvv - 10201.0f * M);
            float uE  = 500.0f * tanhf(rE / 500.0f);
            float ddEv = Evv + 1e-4f * (328.25f * uE - 202.0f * Evv - 10201.0f * E);
            float uI  = 500.0f * tanhf(rI / 500.0f);
            float ddIv = Ivv + 1e-4f * (1122.0f * uI - 102.0f * Ivv - 2601.0f * I);
            M   = satf(ddM);  E   = satf(ddE);  I   = satf(ddI);
            Mvv = satf(ddMv); Evv = satf(ddEv); Ivv = satf(ddIv);
            ring[i * RING + (t & 511)] = M;
            if (h == 9) {
                out[ 4400 + i * 50 + b] = E;
                out[14400 + i * 50 + b] = I;
                out[24400 + i * 50 + b] = M;
                out[34400 + i * 50 + b] = Evv;
                out[44400 + i * 50 + b] = Ivv;
                out[54400 + i * 50 + b] = Mvv;
            }
        }
        __syncthreads();
    }

    if (c == 0 && i < N_NODE) {
        out[3200 + i * 6 + 0] = M;
        out[3200 + i * 6 + 1] = E;
        out[3200 + i * 6 + 2] = I;
        out[3200 + i * 6 + 3] = Mvv;
        out[3200 + i * 6 + 4] = Evv;
        out[3200 + i * 6 + 5] = Ivv;
    }
    for (int p = tid; p < N_NODE * 500; p += 1024) {
        int ii = p / 500, dd = p - ii * 500;
        out[64400 + p] = ring[ii * RING + (499 - dd)];
    }
    __syncthreads();
    for (int p = tid; p < 64 * 50; p += 1024) {
        int o = p / 50, b = p - o * 50;
        float s = 0.0f;
        for (int n = 0; n < N_NODE; ++n)
            s += lmt[o * N_NODE + n] * (out[4400 + n * 50 + b] - out[14400 + n * 50 + b]);
        out[p] = 5.0f * s - 2.0f;
    }
}

extern "C" void kernel_launch(void* const* d_in, const int* in_sizes, int n_in,
                              void* d_out, int out_size, void* d_ws, size_t ws_size,
                              hipStream_t stream) {
    if (ws_size >= WS_NEED) {
        zero_bar<<<1, 64, 0, stream>>>((int*)((float*)d_ws + OFF_BAR));
        jansen_pipe<<<NWG, NTHR, 0, stream>>>(
            (const float*)d_in[0], (const float*)d_in[1], (const float*)d_in[2],
            (const float*)d_in[3], (const float*)d_in[4], (const float*)d_in[5],
            (const float*)d_in[6], (const int*)d_in[7],
            (float*)d_out, (float*)d_ws);
    } else {
        jansen_main<<<1, 1024, 0, stream>>>(
            (const float*)d_in[0], (const float*)d_in[1], (const float*)d_in[2],
            (const float*)d_in[3], (const float*)d_in[4], (const float*)d_in[5],
            (const float*)d_in[6], (const int*)d_in[7],
            (float*)d_out, (float*)d_ws);
    }
}

// Round 3
// 2581.375 us; speedup vs baseline: 1.0606x; 1.0606x over previous
//
#include <hip/hip_runtime.h>
#include <math.h>

#define N_NODE 200
#define RING   512
#define NSTEP  500
#define TB     16
#define NB     32          // ceil(500/16)
#define NWG    8
#define NTHR   512
#define JSL    25          // j-rows per WG slice
#define NEARCAP 32         // near band d < 32 (required for 1-block-ahead far)
#define MDEP   36          // Mrec depth (>= 33), mod-36 slots

// ---- ws layout (float element offsets) ----
#define FPBUF   (NWG * N_NODE * TB)   // 25600 floats per parity buffer
#define OFF_FP  0                     // [2][NWG][200][16] far partials
#define OFF_BAR (2 * FPBUF)           // [64] int barrier counters
#define WS_NEED ((size_t)(2 * FPBUF + 64) * 4)

// ---- static LDS layout (byte offsets into smem[]) ----
#define SM_RED   0                    // double[8]
#define SM_FLG   64                   // int[16]: 0 simC, 1 farC, 2 simDone, 3 ledReady
#define SM_MREC  128                  // float[36*200]
#define SM_NJD   28928                // u32 [200*32]
#define SM_NW    54528                // float[200*32]
#define SM_NCNT  80128                // int[200]
#define SM_LED   80928                // float[2][16][200]
#define SM_RING  106528               // float[25*512]
#define SM_TOTAL 157728
// epilogue overlays (post-loop; do not touch SM_RING until hEb flushed)
#define SM_LMT   128                  // float[64*200]   -> ends 51328
#define SM_DIFF  51328                // float[200*50]   -> ends 91328 (< SM_RING)

__device__ __forceinline__ float sigm(float x) {
    return 5.0f / (1.0f + expf(0.56f * (6.0f - x)));
}
__device__ __forceinline__ float satf(float x) {
    return 1000.0f * tanhf(x / 1000.0f);
}

// barrier among the 4 waves of one half (arrive: lane0 of each wave)
__device__ __forceinline__ void half_barrier(int* c, int tgt) {
    if ((threadIdx.x & 63) == 0)
        __hip_atomic_fetch_add(c, 1, __ATOMIC_RELEASE, __HIP_MEMORY_SCOPE_WORKGROUP);
    while (__hip_atomic_load(c, __ATOMIC_ACQUIRE, __HIP_MEMORY_SCOPE_WORKGROUP) < tgt)
        __builtin_amdgcn_s_sleep(1);
}

__global__ void zero_bar(int* bar) {
    if (threadIdx.x < 64) bar[threadIdx.x] = 0;
}

__global__ __launch_bounds__(NTHR, 1)
void jansen_split(const float* __restrict__ inp, const float* __restrict__ noise_in,
                  const float* __restrict__ hx,  const float* __restrict__ hE,
                  const float* __restrict__ sc,  const float* __restrict__ wbb,
                  const float* __restrict__ lm,  const int*   __restrict__ delays,
                  float* __restrict__ out, float* __restrict__ ws)
{
    __shared__ char smem[SM_TOTAL];
    double*   red  = (double*)(smem + SM_RED);
    int*      flg  = (int*)(smem + SM_FLG);
    float*    Mrec = (float*)(smem + SM_MREC);
    unsigned* nJD  = (unsigned*)(smem + SM_NJD);
    float*    nW   = (float*)(smem + SM_NW);
    int*      nCnt = (int*)(smem + SM_NCNT);
    float*    LEdS = (float*)(smem + SM_LED);
    float*    ringS= (float*)(smem + SM_RING);

    const int  tid   = threadIdx.x;
    const int  wg    = blockIdx.x;
    const bool lower = tid < 256;
    const int  i     = lower ? tid : tid - 256;   // node id (active if < 200)
    const int  jlo   = wg * JSL;

    float* fp  = ws + OFF_FP;
    int*   bar = (int*)(ws + OFF_BAR);

    if (tid == 0) { flg[0] = 0; flg[1] = 0; flg[2] = 0; flg[3] = 1; }

    // ---- pass A: Frobenius norm of wl (redundant per WG) ----
    double ssq = 0.0;
    for (int q = tid; q < N_NODE * N_NODE; q += NTHR) {
        int j = q / N_NODE, ii = q - j * N_NODE;
        float w1 = expf(wbb[ii * N_NODE + j]) * sc[ii * N_NODE + j];
        float w2 = expf(wbb[j * N_NODE + ii]) * sc[j * N_NODE + ii];
        float wl = log1pf(0.5f * (w1 + w2));
        ssq += (double)wl * (double)wl;
    }
    #pragma unroll
    for (int off = 32; off > 0; off >>= 1) ssq += __shfl_down(ssq, off, 64);
    if ((tid & 63) == 0) red[tid >> 6] = ssq;

    // ---- ring init: history M[-1-dd] = hE[j][dd] at slot 511-dd ----
    for (int p = tid; p < JSL * RING; p += NTHR) {
        int jl = p >> 9, x = p & 511;
        int dd = 511 - x;
        ringS[p] = (dd < 500) ? hE[(jlo + jl) * 500 + dd] : 0.0f;
    }
    // ---- Mrec init: M[-q] at slot (36-q), q=1..32 -> slot s in [4,35]: hE[j][35-s] ----
    for (int p = tid; p < MDEP * N_NODE; p += NTHR) {
        int s = p / N_NODE, j = p - s * N_NODE;
        Mrec[p] = (s >= 4) ? hE[j * 500 + (35 - s)] : 0.0f;
    }
    __syncthreads();
    if (tid == 0) {
        double s = 0.0;
        #pragma unroll
        for (int r = 0; r < 8; ++r) s += red[r];
        red[0] = 1.0 / sqrt(s);
    }
    __syncthreads();
    const float inv = (float)red[0];

    // ---- pass B ----
    float rowsum = 0.0f;
    float M = 0, E = 0, I = 0, Mvv = 0, Evv = 0, Ivv = 0;
    float wreg[JSL];
    int   ereg[JSL];
    #pragma unroll
    for (int jl = 0; jl < JSL; ++jl) { wreg[jl] = 0.0f; ereg[jl] = 0; }
    if (lower && i < N_NODE) {
        int cnt = 0;
        for (int j = 0; j < N_NODE; ++j) {
            float w1 = expf(wbb[i * N_NODE + j]) * sc[i * N_NODE + j];
            float w2 = expf(wbb[j * N_NODE + i]) * sc[j * N_NODE + i];
            float w  = log1pf(0.5f * (w1 + w2)) * inv;
            int d = delays[j * N_NODE + i];
            rowsum += w;
            if (d < NEARCAP && cnt < NEARCAP) {
                nJD[i * NEARCAP + cnt] = (unsigned)(j | (d << 16));
                nW [i * NEARCAP + cnt] = w;
                ++cnt;
            }
        }
        nCnt[i] = cnt;
        M   = hx[i * 6 + 0]; E   = hx[i * 6 + 1]; I   = hx[i * 6 + 2];
        Mvv = hx[i * 6 + 3]; Evv = hx[i * 6 + 4]; Ivv = hx[i * 6 + 5];
    }
    if (!lower && i < N_NODE) {
        #pragma unroll
        for (int jl = 0; jl < JSL; ++jl) {
            int j = jlo + jl;
            float w1 = expf(wbb[i * N_NODE + j]) * sc[i * N_NODE + j];
            float w2 = expf(wbb[j * N_NODE + i]) * sc[j * N_NODE + i];
            float w  = log1pf(0.5f * (w1 + w2)) * inv;
            int d = delays[j * N_NODE + i];
            wreg[jl] = (d < NEARCAP) ? 0.0f : w;
            ereg[jl] = 511 - d;
        }
    }
    __syncthreads();

    // ---- prologue: far(0) publish + grid barrier + gather -> LEdS[0] ----
    if (!lower && i < N_NODE) {
        float ac0[16];
        #pragma unroll
        for (int k = 0; k < 16; ++k) ac0[k] = 0.0f;
        #pragma unroll
        for (int jl = 0; jl < JSL; ++jl) {
            float w  = wreg[jl];
            int   p0 = ereg[jl] & 511;
            const float* rb = ringS + (jl << 9);
            #pragma unroll
            for (int k = 0; k < 16; ++k)
                ac0[k] = fmaf(w, rb[(p0 + k) & 511], ac0[k]);
        }
        float4* fpw = (float4*)(fp + wg * (N_NODE * TB) + i * TB);
        fpw[0] = make_float4(ac0[ 0], ac0[ 1], ac0[ 2], ac0[ 3]);
        fpw[1] = make_float4(ac0[ 4], ac0[ 5], ac0[ 6], ac0[ 7]);
        fpw[2] = make_float4(ac0[ 8], ac0[ 9], ac0[10], ac0[11]);
        fpw[3] = make_float4(ac0[12], ac0[13], ac0[14], ac0[15]);
    }
    __syncthreads();   // drains vmcnt for all waves
    if (tid == 0) {
        __threadfence();
        __hip_atomic_fetch_add(&bar[0], 1, __ATOMIC_ACQ_REL, __HIP_MEMORY_SCOPE_AGENT);
        while (__hip_atomic_load(&bar[0], __ATOMIC_ACQUIRE, __HIP_MEMORY_SCOPE_AGENT) < NWG)
            __builtin_amdgcn_s_sleep(2);
        __threadfence();
    }
    __syncthreads();
    if (!lower && i < N_NODE) {
        const float* basep = fp + i * TB;
        #pragma unroll
        for (int c = 0; c < 4; ++c) {
            float sx = 0, sy = 0, sz = 0, sw = 0;
            #pragma unroll
            for (int g = 0; g < NWG; ++g) {
                float4 q = *(const float4*)(basep + g * (N_NODE * TB) + c * 4);
                sx += q.x; sy += q.y; sz += q.z; sw += q.w;
            }
            LEdS[(c * 4 + 0) * N_NODE + i] = sx;
            LEdS[(c * 4 + 1) * N_NODE + i] = sy;
            LEdS[(c * 4 + 2) * N_NODE + i] = sz;
            LEdS[(c * 4 + 3) * N_NODE + i] = sw;
        }
    }
    __syncthreads();

    // ---------------- main loop: sim waves || far waves ----------------
    int simTgt = 4, farTgt = 4;
    for (int b = 0; b < NB; ++b) {
        if (lower) {
            // wait LEdS for block b ready
            while (__hip_atomic_load(&flg[3], __ATOMIC_ACQUIRE, __HIP_MEMORY_SCOPE_WORKGROUP) < b + 1)
                __builtin_amdgcn_s_sleep(1);
            const int t0   = b * TB;
            const int led  = (b & 1) * 3200;
            const int kmax = (NSTEP - t0 < TB) ? (NSTEP - t0) : TB;
            const int t0m  = t0 % MDEP;
            // prime u/n register pipeline (depth 3)
            float u0=0, u1=0, u2=0, n0=0, n1=0, n2=0;
            if (i < N_NODE) {
                int ta = t0, tb2 = t0 + 1, tc = t0 + 2;
                int ba = ta / 10, ha = ta - 10 * ba;
                int bb = tb2 / 10, hb = tb2 - 10 * bb;
                int bc = tc / 10, hc = tc - 10 * bc;
                u0 = inp     [i * 500 + ha * 50 + ba];
                n0 = noise_in[i * 500 + ha * 50 + ba];
                u1 = inp     [i * 500 + hb * 50 + bb];
                n1 = noise_in[i * 500 + hb * 50 + bb];
                u2 = inp     [i * 500 + hc * 50 + bc];
                n2 = noise_in[i * 500 + hc * 50 + bc];
            }
            for (int k = 0; k < kmax; ++k) {
                const int t = t0 + k;
                if (i < N_NODE) {
                    float LEd = LEdS[led + k * N_NODE + i];
                    int cnt = nCnt[i];
                    int s36 = t0m + k; if (s36 >= MDEP) s36 -= MDEP;
                    for (int n = 0; n < cnt; ++n) {
                        unsigned jd = nJD[i * NEARCAP + n];
                        int j = jd & 0xffff, d = (int)(jd >> 16);
                        int r = s36 - 1 - d; if (r < 0) r += MDEP;
                        LEd = fmaf(nW[i * NEARCAP + n], Mrec[r * N_NODE + j], LEd);
                    }
                    float u  = u0;
                    float nz = n0;
                    float rM = sigm(E - I);
                    float rE = 250.0f * nz + 1000.01f * (LEd - rowsum * E) + 108.01f * sigm(135.01f * M);
                    float rI = 33.76f * sigm(33.76f * M);
                    float ddM = M + 1e-4f * Mvv;
                    float ddE = E + 1e-4f * Evv;
                    float ddI = I + 1e-4f * Ivv;
                    float uu  = u + 500.0f * tanhf(rM / 500.0f);
                    float ddMv = Mvv + 1e-4f * (328.25f * uu - 202.0f * Mvv - 10201.0f * M);
                    float uE  = 500.0f * tanhf(rE / 500.0f);
                    float ddEv = Evv + 1e-4f * (328.25f * uE - 202.0f * Evv - 10201.0f * E);
                    float uI  = 500.0f * tanhf(rI / 500.0f);
                    float ddIv = Ivv + 1e-4f * (1122.0f * uI - 102.0f * Ivv - 2601.0f * I);
                    M   = satf(ddM);  E   = satf(ddE);  I   = satf(ddI);
                    Mvv = satf(ddMv); Evv = satf(ddEv); Ivv = satf(ddIv);
                    Mrec[s36 * N_NODE + i] = M;
                    if (i >= jlo && i < jlo + JSL) {
                        ringS[((i - jlo) << 9) | (t & 511)] = M;
                    }
                    if (wg == 0) {
                        int bb2 = t / 10, h = t - 10 * bb2;
                        if (h == 9) {
                            out[ 4400 + i * 50 + bb2] = E;
                            out[14400 + i * 50 + bb2] = I;
                            out[24400 + i * 50 + bb2] = M;
                            out[34400 + i * 50 + bb2] = Evv;
                            out[44400 + i * 50 + bb2] = Ivv;
                            out[54400 + i * 50 + bb2] = Mvv;
                        }
                    }
                    // rotate u/n pipeline, issue t+3
                    u0 = u1; u1 = u2; n0 = n1; n1 = n2;
                    int t3 = t + 3;
                    if (t3 < NSTEP) {
                        int b3 = t3 / 10, h3 = t3 - 10 * b3;
                        u2 = inp     [i * 500 + h3 * 50 + b3];
                        n2 = noise_in[i * 500 + h3 * 50 + b3];
                    }
                }
                half_barrier(&flg[0], simTgt); simTgt += 4;
            }
            if (tid == 0)
                __hip_atomic_fetch_add(&flg[2], 1, __ATOMIC_RELEASE, __HIP_MEMORY_SCOPE_WORKGROUP);
        } else {
            if (b < NB - 1) {
                const int tb = b + 1;
                // need sim(b-1) complete before reading ring / overwriting LEdS parity
                while (__hip_atomic_load(&flg[2], __ATOMIC_ACQUIRE, __HIP_MEMORY_SCOPE_WORKGROUP) < b)
                    __builtin_amdgcn_s_sleep(1);
                const int t1   = tb * TB;
                const int ledn = (tb & 1) * 3200;
                float* fpn = fp + (tb & 1) * FPBUF;
                if (i < N_NODE) {
                    float ac[16];
                    #pragma unroll
                    for (int k = 0; k < 16; ++k) ac[k] = 0.0f;
                    #pragma unroll
                    for (int jl = 0; jl < JSL; ++jl) {
                        float w  = wreg[jl];
                        int   p0 = (t1 + ereg[jl]) & 511;
                        const float* rb = ringS + (jl << 9);
                        #pragma unroll
                        for (int k = 0; k < 16; ++k)
                            ac[k] = fmaf(w, rb[(p0 + k) & 511], ac[k]);
                    }
                    float4* fpw = (float4*)(fpn + wg * (N_NODE * TB) + i * TB);
                    fpw[0] = make_float4(ac[ 0], ac[ 1], ac[ 2], ac[ 3]);
                    fpw[1] = make_float4(ac[ 4], ac[ 5], ac[ 6], ac[ 7]);
                    fpw[2] = make_float4(ac[ 8], ac[ 9], ac[10], ac[11]);
                    fpw[3] = make_float4(ac[12], ac[13], ac[14], ac[15]);
                }
                asm volatile("s_waitcnt vmcnt(0)" ::: "memory");
                half_barrier(&flg[1], farTgt); farTgt += 4;
                if (tid == 256) {
                    __threadfence();
                    __hip_atomic_fetch_add(&bar[tb], 1, __ATOMIC_ACQ_REL, __HIP_MEMORY_SCOPE_AGENT);
                    while (__hip_atomic_load(&bar[tb], __ATOMIC_ACQUIRE, __HIP_MEMORY_SCOPE_AGENT) < NWG)
                        __builtin_amdgcn_s_sleep(2);
                    __threadfence();
                }
                half_barrier(&flg[1], farTgt); farTgt += 4;
                if (i < N_NODE) {
                    const float* basep = fpn + i * TB;
                    #pragma unroll
                    for (int c = 0; c < 4; ++c) {
                        float sx = 0, sy = 0, sz = 0, sw = 0;
                        #pragma unroll
                        for (int g = 0; g < NWG; ++g) {
                            float4 q = *(const float4*)(basep + g * (N_NODE * TB) + c * 4);
                            sx += q.x; sy += q.y; sz += q.z; sw += q.w;
                        }
                        LEdS[ledn + (c * 4 + 0) * N_NODE + i] = sx;
                        LEdS[ledn + (c * 4 + 1) * N_NODE + i] = sy;
                        LEdS[ledn + (c * 4 + 2) * N_NODE + i] = sz;
                        LEdS[ledn + (c * 4 + 3) * N_NODE + i] = sw;
                    }
                }
                half_barrier(&flg[1], farTgt); farTgt += 4;
                if (tid == 256)
                    __hip_atomic_fetch_add(&flg[3], 1, __ATOMIC_RELEASE, __HIP_MEMORY_SCOPE_WORKGROUP);
            }
        }
    }
    __syncthreads();

    // ---------------- epilogue ----------------
    for (int p = tid; p < JSL * 500; p += NTHR) {
        int jl = p / 500, dd = p - jl * 500;
        out[64400 + (jlo + jl) * 500 + dd] = ringS[(jl << 9) + ((499 - dd) & 511)];
    }
    if (wg != 0) return;

    if (lower && i < N_NODE) {
        out[3200 + i * 6 + 0] = M;
        out[3200 + i * 6 + 1] = E;
        out[3200 + i * 6 + 2] = I;
        out[3200 + i * 6 + 3] = Mvv;
        out[3200 + i * 6 + 4] = Evv;
        out[3200 + i * 6 + 5] = Ivv;
    }

    float* lmt  = (float*)(smem + SM_LMT);
    float* diff = (float*)(smem + SM_DIFF);
    __syncthreads();
    if (tid < 64) {
        float s = 0.0f;
        for (int n = 0; n < N_NODE; ++n) { float v = lm[tid * N_NODE + n]; s += v * v; }
        float ivn = 1.0f / sqrtf(s);
        for (int n = 0; n < N_NODE; ++n) lmt[tid * N_NODE + n] = lm[tid * N_NODE + n] * ivn;
    }
    __syncthreads();
    if (tid < N_NODE) {
        float s = 0.0f;
        for (int o = 0; o < 64; ++o) s += lmt[o * N_NODE + tid];
        s *= (1.0f / 64.0f);
        for (int o = 0; o < 64; ++o) lmt[o * N_NODE + tid] -= s;
    }
    __syncthreads();
    for (int p = tid; p < 10000; p += NTHR) diff[p] = out[4400 + p] - out[14400 + p];
    __syncthreads();
    for (int p = tid; p < 3200; p += NTHR) {
        int o = p / 50, bb = p - o * 50;
        float s = 0.0f;
        for (int n = 0; n < N_NODE; ++n)
            s = fmaf(lmt[o * N_NODE + n], diff[n * 50 + bb], s);
        out[p] = 5.0f * s - 2.0f;
    }
}

// ---------------- fallback: single-WG kernel ----------------
__global__ __launch_bounds__(1024, 1)
void jansen_main(const float* __restrict__ inp, const float* __restrict__ noise_in,
                 const float* __restrict__ hx,  const float* __restrict__ hE,
                 const float* __restrict__ sc,  const float* __restrict__ wbb,
                 const float* __restrict__ lm,  const int*   __restrict__ delays,
                 float* __restrict__ out, float* __restrict__ ws)
{
    const int tid = threadIdx.x;
    const int i   = tid & 255;
    const int c   = tid >> 8;

    float* ring = ws;
    float* lmt  = ws + N_NODE * RING;

    __shared__ double red[18];
    __shared__ float  part[4][N_NODE];
    __shared__ float  wn[N_NODE * N_NODE];

    double ssq = 0.0;
    for (int p = tid; p < N_NODE * N_NODE; p += 1024) {
        int r0 = p / N_NODE;
        int cc = p - r0 * N_NODE;
        float w1 = expf(wbb[p]) * sc[p];
        float w2 = expf(wbb[cc * N_NODE + r0]) * sc[cc * N_NODE + r0];
        float v  = log1pf(0.5f * (w1 + w2));
        wn[p] = v;
        ssq += (double)v * (double)v;
    }
    #pragma unroll
    for (int off = 32; off > 0; off >>= 1) ssq += __shfl_down(ssq, off, 64);
    if ((tid & 63) == 0) red[tid >> 6] = ssq;
    __syncthreads();
    if (tid == 0) {
        double s = 0.0;
        for (int k = 0; k < 16; ++k) s += red[k];
        red[16] = 1.0 / sqrt(s);
    }
    __syncthreads();
    const float inv_norm = (float)red[16];
    for (int p = tid; p < N_NODE * N_NODE; p += 1024) wn[p] *= inv_norm;

    for (int p = tid; p < N_NODE * 500; p += 1024) {
        int j = p / 500, dd = p - j * 500;
        ring[j * RING + (511 - dd)] = hE[p];
    }
    if (tid < 64) {
        float s = 0.0f;
        for (int n = 0; n < N_NODE; ++n) { float v = lm[tid * N_NODE + n]; s += v * v; }
        float inv = 1.0f / sqrtf(s);
        for (int n = 0; n < N_NODE; ++n) lmt[tid * N_NODE + n] = lm[tid * N_NODE + n] * inv;
    }
    __syncthreads();
    if (tid < N_NODE) {
        float s = 0.0f;
        for (int o = 0; o < 64; ++o) s += lmt[o * N_NODE + tid];
        s *= (1.0f / 64.0f);
        for (int o = 0; o < 64; ++o) lmt[o * N_NODE + tid] -= s;
    }

    unsigned int dpk[25];
    if (i < N_NODE) {
        #pragma unroll
        for (int r0 = 0; r0 < 25; ++r0) {
            int d0 = delays[(c * 50 + 2 * r0    ) * N_NODE + i];
            int d1 = delays[(c * 50 + 2 * r0 + 1) * N_NODE + i];
            unsigned e0 = (unsigned)((-1 - d0) & 511);
            unsigned e1 = (unsigned)((-1 - d1) & 511);
            dpk[r0] = e0 | (e1 << 16);
        }
    }

    float M = 0, E = 0, I = 0, Mvv = 0, Evv = 0, Ivv = 0, rowsum = 0;
    if (c == 0 && i < N_NODE) {
        M   = hx[i * 6 + 0]; E   = hx[i * 6 + 1]; I   = hx[i * 6 + 2];
        Mvv = hx[i * 6 + 3]; Evv = hx[i * 6 + 4]; Ivv = hx[i * 6 + 5];
    }
    __syncthreads();
    if (c == 0 && i < N_NODE) {
        float s = 0.0f;
        for (int j = 0; j < N_NODE; ++j) s += wn[j * N_NODE + i];
        rowsum = s;
    }

    for (int t = 0; t < NSTEP; ++t) {
        if (i < N_NODE) {
            float acc = 0.0f;
            const float* ringc = ring + c * 50 * RING;
            const float* wnc   = wn + c * 50 * N_NODE + i;
            #pragma unroll
            for (int r0 = 0; r0 < 50; ++r0) {
                unsigned e = (dpk[r0 >> 1] >> ((r0 & 1) << 4)) & 0xffffu;
                int pos = (int)(((unsigned)t + e) & 511u);
                acc = fmaf(wnc[r0 * N_NODE], ringc[r0 * RING + pos], acc);
            }
            part[c][i] = acc;
        }
        __syncthreads();
        if (c == 0 && i < N_NODE) {
            float LEd = part[0][i] + part[1][i] + part[2][i] + part[3][i];
            int b = t / 10, h = t - b * 10;
            float u  = inp     [i * 500 + h * 50 + b];
            float nz = noise_in[i * 500 + h * 50 + b];
            float rM = sigm(E - I);
            float rE = 250.0f * nz + 1000.01f * (LEd - rowsum * E) + 108.01f * sigm(135.01f * M);
            float rI = 33.76f * sigm(33.76f * M);
            float ddM = M + 1e-4f * Mvv;
            float ddE = E + 1e-4f * Evv;
            float ddI = I + 1e-4f * Ivv;
            float uu  = u + 500.0f * tanhf(rM / 500.0f);
            float ddMv = Mvv + 1e-4f * (328.25f * uu - 202.0f * Mvv - 10201.0f * M);
            float uE  = 500.0f * tanhf(rE / 500.0f);
            float ddEv = Evv + 1e-4f * (328.25f * uE - 202.0f * Evv - 10201.0f * E);
            float uI  = 500.0f * tanhf(rI / 500.0f);
            float ddIv = Ivv + 1e-4f * (1122.0f * uI - 102.0f * Ivv - 2601.0f * I);
            M   = satf(ddM);  E   = satf(ddE);  I   = satf(ddI);
            Mvv = satf(ddMv); Evv = satf(ddEv); Ivv = satf(ddIv);
            ring[i * RING + (t & 511)] = M;
            if (h == 9) {
                out[ 4400 + i * 50 + b] = E;
                out[14400 + i * 50 + b] = I;
                out[24400 + i * 50 + b] = M;
                out[34400 + i * 50 + b] = Evv;
                out[44400 + i * 50 + b] = Ivv;
                out[54400 + i * 50 + b] = Mvv;
            }
        }
        __syncthreads();
    }

    if (c == 0 && i < N_NODE) {
        out[3200 + i * 6 + 0] = M;
        out[3200 + i * 6 + 1] = E;
        out[3200 + i * 6 + 2] = I;
        out[3200 + i * 6 + 3] = Mvv;
        out[3200 + i * 6 + 4] = Evv;
        out[3200 + i * 6 + 5] = Ivv;
    }
    for (int p = tid; p < N_NODE * 500; p += 1024) {
        int ii = p / 500, dd = p - ii * 500;
        out[64400 + p] = ring[ii * RING + (499 - dd)];
    }
    __syncthreads();
    for (int p = tid; p < 64 * 50; p += 1024) {
        int o = p / 50, b = p - o * 50;
        float s = 0.0f;
        for (int n = 0; n < N_NODE; ++n)
            s += lmt[o * N_NODE + n] * (out[4400 + n * 50 + b] - out[14400 + n * 50 + b]);
        out[p] = 5.0f * s - 2.0f;
    }
}

extern "C" void kernel_launch(void* const* d_in, const int* in_sizes, int n_in,
                              void* d_out, int out_size, void* d_ws, size_t ws_size,
                              hipStream_t stream) {
    if (ws_size >= WS_NEED) {
        zero_bar<<<1, 64, 0, stream>>>((int*)((float*)d_ws + OFF_BAR));
        jansen_split<<<NWG, NTHR, 0, stream>>>(
            (const float*)d_in[0], (const float*)d_in[1], (const float*)d_in[2],
            (const float*)d_in[3], (const float*)d_in[4], (const float*)d_in[5],
            (const float*)d_in[6], (const int*)d_in[7],
            (float*)d_out, (float*)d_ws);
    } else {
        jansen_main<<<1, 1024, 0, stream>>>(
            (const float*)d_in[0], (const float*)d_in[1], (const float*)d_in[2],
            (const float*)d_in[3], (const float*)d_in[4], (const float*)d_in[5],
            (const float*)d_in[6], (const int*)d_in[7],
            (float*)d_out, (float*)d_ws);
    }
}

// Round 4
// 2000.103 us; speedup vs baseline: 1.3688x; 1.2906x over previous
//
#include <hip/hip_runtime.h>
#include <math.h>

#define N_NODE 200
#define RING   512
#define ROWF   545          // 512 + 32 mirror pad + 1 stagger (odd stride -> conflict-free ring writes)
#define NSTEP  500
#define TB     32
#define NB     16           // ceil(500/32); last block kmax=20
#define NWG    8
#define NTHR   256
#define JSL    25           // j-rows per WG slice
#define NEARCAP 32          // near band d < 32
#define MDEP   36           // Mrec depth (>= 33), mod-36 slots

// ---- ws layout (float element offsets) ----
#define FPBUF   (NWG * N_NODE * TB)   // 51200 floats per parity buffer
#define OFF_FP  0                     // [2][NWG][200][32] far partials (parity by block&1)
#define OFF_BAR (2 * FPBUF)           // [64] int barrier counters
#define WS_NEED ((size_t)(2 * FPBUF + 64) * 4)

// ---- static LDS layout (byte offsets into smem[]) ----
#define SM_RED   0        // double[8]
#define SM_MREC  64       // float[36*200]            -> 28864
#define SM_NOFF  28864    // u32 [32][200] TRANSPOSED -> 54464
#define SM_NW    54464    // float[32][200] TRANSPOSED-> 80064
#define SM_NCNT  80064    // int[200]                 -> 80864
#define SM_LED   80864    // float[32*200]            -> 106464
#define SM_RING  106464   // float[25*545] = 54500B   -> 160964
#define SM_TOTAL 160964
// epilogue overlays (post-loop; must stay below SM_RING until hEb flushed)
#define SM_LMT   64       // float[64*200]  -> 51264
#define SM_DIFF  51264    // float[200*50]  -> 91264

__device__ __forceinline__ float sigm(float x) {
    return 5.0f / (1.0f + expf(0.56f * (6.0f - x)));
}
__device__ __forceinline__ float satf(float x) {
    return 1000.0f * tanhf(x / 1000.0f);
}

__device__ __forceinline__ void grid_barrier(int* slot, int nwg) {
    __syncthreads();
    if (threadIdx.x == 0) {
        __threadfence();
        __hip_atomic_fetch_add(slot, 1, __ATOMIC_ACQ_REL, __HIP_MEMORY_SCOPE_AGENT);
        while (__hip_atomic_load(slot, __ATOMIC_ACQUIRE, __HIP_MEMORY_SCOPE_AGENT) < nwg) {
            __builtin_amdgcn_s_sleep(2);
        }
        __threadfence();
    }
    __syncthreads();
}

__global__ void zero_bar(int* bar) {
    if (threadIdx.x < 64) bar[threadIdx.x] = 0;
}

__global__ __launch_bounds__(NTHR, 1)
void jansen_tb32(const float* __restrict__ inp, const float* __restrict__ noise_in,
                 const float* __restrict__ hx,  const float* __restrict__ hE,
                 const float* __restrict__ sc,  const float* __restrict__ wbb,
                 const float* __restrict__ lm,  const int*   __restrict__ delays,
                 float* __restrict__ out, float* __restrict__ ws)
{
    __shared__ char smem[SM_TOTAL];
    double*   red  = (double*)(smem + SM_RED);
    float*    Mrec = (float*)(smem + SM_MREC);
    unsigned* nOFF = (unsigned*)(smem + SM_NOFF);
    float*    nW   = (float*)(smem + SM_NW);
    int*      nCnt = (int*)(smem + SM_NCNT);
    float*    LEdS = (float*)(smem + SM_LED);
    float*    ringS= (float*)(smem + SM_RING);

    const int tid = threadIdx.x;
    const int wg  = blockIdx.x;
    const int i   = tid;            // node id (active if < 200)
    const int jlo = wg * JSL;

    float* fp  = ws + OFF_FP;
    int*   bar = (int*)(ws + OFF_BAR);

    // ---- pass A: Frobenius norm of wl (redundant per WG) ----
    double ssq = 0.0;
    for (int q = tid; q < N_NODE * N_NODE; q += NTHR) {
        int j = q / N_NODE, ii = q - j * N_NODE;
        float w1 = expf(wbb[ii * N_NODE + j]) * sc[ii * N_NODE + j];
        float w2 = expf(wbb[j * N_NODE + ii]) * sc[j * N_NODE + ii];
        float wl = log1pf(0.5f * (w1 + w2));
        ssq += (double)wl * (double)wl;
    }
    #pragma unroll
    for (int off = 32; off > 0; off >>= 1) ssq += __shfl_down(ssq, off, 64);
    if ((tid & 63) == 0) red[tid >> 6] = ssq;

    // ---- ring init: pos x holds M[-1-dd], dd=511-x; mirror [512..543] copies [0..31] ----
    for (int p = tid; p < JSL * ROWF; p += NTHR) {
        int jl = p / ROWF, x = p - jl * ROWF;
        float v = 0.0f;
        if (x < 544) {
            int dd = (x < RING) ? (511 - x) : (1023 - x);
            if (dd < 500) v = hE[(jlo + jl) * 500 + dd];
        }
        ringS[p] = v;
    }
    // ---- Mrec init: M[-q] at slot (36-q), q=1..32 -> slot s in [4,35]: hE[j][35-s] ----
    for (int p = tid; p < MDEP * N_NODE; p += NTHR) {
        int s = p / N_NODE, j = p - s * N_NODE;
        Mrec[p] = (s >= 4) ? hE[j * 500 + (35 - s)] : 0.0f;
    }
    __syncthreads();
    if (tid == 0) {
        double s = 0.0;
        #pragma unroll
        for (int r = 0; r < 8; ++r) s += red[r];
        red[0] = 1.0 / sqrt(s);
    }
    __syncthreads();
    const float inv = (float)red[0];

    // ---- pass B: near lists (transposed, packed offsets), own-slice far weights, state ----
    float rowsum = 0.0f;
    float M = 0, E = 0, I = 0, Mvv = 0, Evv = 0, Ivv = 0;
    float wreg[JSL];
    int   ereg[JSL];
    #pragma unroll
    for (int jl = 0; jl < JSL; ++jl) { wreg[jl] = 0.0f; ereg[jl] = 0; }
    int cnt = 0;
    if (i < N_NODE) {
        for (int j = 0; j < N_NODE; ++j) {
            float w1 = expf(wbb[i * N_NODE + j]) * sc[i * N_NODE + j];
            float w2 = expf(wbb[j * N_NODE + i]) * sc[j * N_NODE + i];
            float w  = log1pf(0.5f * (w1 + w2)) * inv;
            int d = delays[j * N_NODE + i];
            rowsum += w;
            if (d < NEARCAP && cnt < NEARCAP) {
                nOFF[cnt * N_NODE + i] = (unsigned)((35 - d) * N_NODE + j);
                nW  [cnt * N_NODE + i] = w;
                ++cnt;
            }
        }
        nCnt[i] = cnt;
        #pragma unroll
        for (int jl = 0; jl < JSL; ++jl) {
            int j = jlo + jl;
            float w1 = expf(wbb[i * N_NODE + j]) * sc[i * N_NODE + j];
            float w2 = expf(wbb[j * N_NODE + i]) * sc[j * N_NODE + i];
            float w  = log1pf(0.5f * (w1 + w2)) * inv;
            int d = delays[j * N_NODE + i];
            wreg[jl] = (d < NEARCAP) ? 0.0f : w;
            ereg[jl] = 511 - d;
        }
        M   = hx[i * 6 + 0]; E   = hx[i * 6 + 1]; I   = hx[i * 6 + 2];
        Mvv = hx[i * 6 + 3]; Evv = hx[i * 6 + 4]; Ivv = hx[i * 6 + 5];
    }
    __syncthreads();

    // ---------------- main loop over 32-step blocks (serial phases) ----------------
    for (int b = 0; b < NB; ++b) {
        const int t0 = b * TB;
        float* fpb = fp + (b & 1) * FPBUF;

        float u0=0, u1=0, u2=0, n0=0, n1=0, n2=0;

        // ---- far phase: own j-slice, contiguous mirror-padded reads ----
        if (i < N_NODE) {
            float ac[TB];
            #pragma unroll
            for (int k = 0; k < TB; ++k) ac[k] = 0.0f;
            #pragma unroll
            for (int jl = 0; jl < JSL; ++jl) {
                float w  = wreg[jl];
                int   p0 = (t0 + ereg[jl]) & 511;
                const float* rb = ringS + jl * ROWF + p0;
                #pragma unroll
                for (int k = 0; k < TB; ++k)
                    ac[k] = fmaf(w, rb[k], ac[k]);
            }
            float4* fpw = (float4*)(fpb + wg * (N_NODE * TB) + i * TB);
            #pragma unroll
            for (int q = 0; q < 8; ++q)
                fpw[q] = make_float4(ac[4*q+0], ac[4*q+1], ac[4*q+2], ac[4*q+3]);

            // prime u/n depth-3 register pipeline (latency hides under barrier+gather)
            {
                int ta = t0, tb2 = t0 + 1, tc = t0 + 2;
                int ba = ta / 10,  ha = ta  - 10 * ba;
                int bbq = tb2 / 10, hb = tb2 - 10 * bbq;
                int bc = tc / 10,  hc = tc  - 10 * bc;
                u0 = inp     [i * 500 + ha * 50 + ba];
                n0 = noise_in[i * 500 + ha * 50 + ba];
                u1 = inp     [i * 500 + hb * 50 + bbq];
                n1 = noise_in[i * 500 + hb * 50 + bbq];
                u2 = inp     [i * 500 + hc * 50 + bc];
                n2 = noise_in[i * 500 + hc * 50 + bc];
            }
        }

        grid_barrier(bar + b, NWG);

        // ---- gather partials: 8 rounds of 8 float4 loads ----
        if (i < N_NODE) {
            const float* basep = fpb + i * TB;
            #pragma unroll
            for (int c = 0; c < 8; ++c) {
                float sx = 0, sy = 0, sz = 0, sw = 0;
                #pragma unroll
                for (int g = 0; g < NWG; ++g) {
                    float4 q = *(const float4*)(basep + g * (N_NODE * TB) + c * 4);
                    sx += q.x; sy += q.y; sz += q.z; sw += q.w;
                }
                LEdS[(c * 4 + 0) * N_NODE + i] = sx;
                LEdS[(c * 4 + 1) * N_NODE + i] = sy;
                LEdS[(c * 4 + 2) * N_NODE + i] = sz;
                LEdS[(c * 4 + 3) * N_NODE + i] = sw;
            }
        }
        __syncthreads();

        // ---- inner per-step phase (redundant in every WG) ----
        const int kmax = (NSTEP - t0 < TB) ? (NSTEP - t0) : TB;
        int s36 = t0 % MDEP;
        int t3  = t0 + 3;
        int bb3 = t3 / 10, hh3 = t3 - 10 * bb3;
        int bcur = t0 / 10, hcur = t0 - 10 * bcur;
        const bool ringw = (i >= jlo) && (i < jlo + JSL);
        const int  rbase = (i - jlo) * ROWF;
        for (int k = 0; k < kmax; ++k) {
            const int t = t0 + k;
            if (i < N_NODE) {
                float LEd = LEdS[k * N_NODE + i];
                const int base36 = s36 * N_NODE;
                for (int n = 0; n < cnt; ++n) {
                    int addr = base36 + (int)nOFF[n * N_NODE + i];
                    if (addr >= MDEP * N_NODE) addr -= MDEP * N_NODE;
                    LEd = fmaf(nW[n * N_NODE + i], Mrec[addr], LEd);
                }
                float u  = u0;
                float nz = n0;
                float rM = sigm(E - I);
                float rE = 250.0f * nz + 1000.01f * (LEd - rowsum * E) + 108.01f * sigm(135.01f * M);
                float rI = 33.76f * sigm(33.76f * M);
                float ddM = M + 1e-4f * Mvv;
                float ddE = E + 1e-4f * Evv;
                float ddI = I + 1e-4f * Ivv;
                float uu  = u + 500.0f * tanhf(rM / 500.0f);
                float ddMv = Mvv + 1e-4f * (328.25f * uu - 202.0f * Mvv - 10201.0f * M);
                float uE  = 500.0f * tanhf(rE / 500.0f);
                float ddEv = Evv + 1e-4f * (328.25f * uE - 202.0f * Evv - 10201.0f * E);
                float uI  = 500.0f * tanhf(rI / 500.0f);
                float ddIv = Ivv + 1e-4f * (1122.0f * uI - 102.0f * Ivv - 2601.0f * I);
                M   = satf(ddM);  E   = satf(ddE);  I   = satf(ddI);
                Mvv = satf(ddMv); Evv = satf(ddEv); Ivv = satf(ddIv);
                Mrec[s36 * N_NODE + i] = M;
                if (ringw) {
                    int pt = t & 511;
                    ringS[rbase + pt] = M;
                    if (pt < 32) ringS[rbase + pt + 512] = M;
                }
                if (wg == 0 && hcur == 9) {
                    out[ 4400 + i * 50 + bcur] = E;
                    out[14400 + i * 50 + bcur] = I;
                    out[24400 + i * 50 + bcur] = M;
                    out[34400 + i * 50 + bcur] = Evv;
                    out[44400 + i * 50 + bcur] = Ivv;
                    out[54400 + i * 50 + bcur] = Mvv;
                }
                // rotate u/n pipeline; issue load for t+3
                u0 = u1; u1 = u2; n0 = n1; n1 = n2;
                if (t3 < NSTEP) {
                    u2 = inp     [i * 500 + hh3 * 50 + bb3];
                    n2 = noise_in[i * 500 + hh3 * 50 + bb3];
                }
                ++t3; ++hh3; if (hh3 == 10) { hh3 = 0; ++bb3; }
                ++hcur; if (hcur == 10) { hcur = 0; ++bcur; }
                ++s36; if (s36 == MDEP) s36 = 0;
            }
            __syncthreads();
        }
    }

    // ---------------- epilogue ----------------
    // hEb slice: rows [jlo, jlo+JSL) from LDS ring
    for (int p = tid; p < JSL * 500; p += NTHR) {
        int jl = p / 500, dd = p - jl * 500;
        out[64400 + (jlo + jl) * 500 + dd] = ringS[jl * ROWF + ((499 - dd) & 511)];
    }
    if (wg != 0) return;

    if (i < N_NODE) {
        out[3200 + i * 6 + 0] = M;
        out[3200 + i * 6 + 1] = E;
        out[3200 + i * 6 + 2] = I;
        out[3200 + i * 6 + 3] = Mvv;
        out[3200 + i * 6 + 4] = Evv;
        out[3200 + i * 6 + 5] = Ivv;
    }

    float* lmt  = (float*)(smem + SM_LMT);
    float* diff = (float*)(smem + SM_DIFF);
    __syncthreads();
    if (tid < 64) {
        float s = 0.0f;
        for (int n = 0; n < N_NODE; ++n) { float v = lm[tid * N_NODE + n]; s += v * v; }
        float ivn = 1.0f / sqrtf(s);
        for (int n = 0; n < N_NODE; ++n) lmt[tid * N_NODE + n] = lm[tid * N_NODE + n] * ivn;
    }
    __syncthreads();
    if (tid < N_NODE) {
        float s = 0.0f;
        for (int o = 0; o < 64; ++o) s += lmt[o * N_NODE + tid];
        s *= (1.0f / 64.0f);
        for (int o = 0; o < 64; ++o) lmt[o * N_NODE + tid] -= s;
    }
    __syncthreads();
    for (int p = tid; p < 10000; p += NTHR) diff[p] = out[4400 + p] - out[14400 + p];
    __syncthreads();
    for (int p = tid; p < 3200; p += NTHR) {
        int o = p / 50, bb = p - o * 50;
        float s = 0.0f;
        for (int n = 0; n < N_NODE; ++n)
            s = fmaf(lmt[o * N_NODE + n], diff[n * 50 + bb], s);
        out[p] = 5.0f * s - 2.0f;
    }
}

// ---------------- fallback: single-WG kernel ----------------
__global__ __launch_bounds__(1024, 1)
void jansen_main(const float* __restrict__ inp, const float* __restrict__ noise_in,
                 const float* __restrict__ hx,  const float* __restrict__ hE,
                 const float* __restrict__ sc,  const float* __restrict__ wbb,
                 const float* __restrict__ lm,  const int*   __restrict__ delays,
                 float* __restrict__ out, float* __restrict__ ws)
{
    const int tid = threadIdx.x;
    const int i   = tid & 255;
    const int c   = tid >> 8;

    float* ring = ws;
    float* lmt  = ws + N_NODE * RING;

    __shared__ double red[18];
    __shared__ float  part[4][N_NODE];
    __shared__ float  wn[N_NODE * N_NODE];

    double ssq = 0.0;
    for (int p = tid; p < N_NODE * N_NODE; p += 1024) {
        int r0 = p / N_NODE;
        int cc = p - r0 * N_NODE;
        float w1 = expf(wbb[p]) * sc[p];
        float w2 = expf(wbb[cc * N_NODE + r0]) * sc[cc * N_NODE + r0];
        float v  = log1pf(0.5f * (w1 + w2));
        wn[p] = v;
        ssq += (double)v * (double)v;
    }
    #pragma unroll
    for (int off = 32; off > 0; off >>= 1) ssq += __shfl_down(ssq, off, 64);
    if ((tid & 63) == 0) red[tid >> 6] = ssq;
    __syncthreads();
    if (tid == 0) {
        double s = 0.0;
        for (int k = 0; k < 16; ++k) s += red[k];
        red[16] = 1.0 / sqrt(s);
    }
    __syncthreads();
    const float inv_norm = (float)red[16];
    for (int p = tid; p < N_NODE * N_NODE; p += 1024) wn[p] *= inv_norm;

    for (int p = tid; p < N_NODE * 500; p += 1024) {
        int j = p / 500, dd = p - j * 500;
        ring[j * RING + (511 - dd)] = hE[p];
    }
    if (tid < 64) {
        float s = 0.0f;
        for (int n = 0; n < N_NODE; ++n) { float v = lm[tid * N_NODE + n]; s += v * v; }
        float inv = 1.0f / sqrtf(s);
        for (int n = 0; n < N_NODE; ++n) lmt[tid * N_NODE + n] = lm[tid * N_NODE + n] * inv;
    }
    __syncthreads();
    if (tid < N_NODE) {
        float s = 0.0f;
        for (int o = 0; o < 64; ++o) s += lmt[o * N_NODE + tid];
        s *= (1.0f / 64.0f);
        for (int o = 0; o < 64; ++o) lmt[o * N_NODE + tid] -= s;
    }

    unsigned int dpk[25];
    if (i < N_NODE) {
        #pragma unroll
        for (int r0 = 0; r0 < 25; ++r0) {
            int d0 = delays[(c * 50 + 2 * r0    ) * N_NODE + i];
            int d1 = delays[(c * 50 + 2 * r0 + 1) * N_NODE + i];
            unsigned e0 = (unsigned)((-1 - d0) & 511);
            unsigned e1 = (unsigned)((-1 - d1) & 511);
            dpk[r0] = e0 | (e1 << 16);
        }
    }

    float M = 0, E = 0, I = 0, Mvv = 0, Evv = 0, Ivv = 0, rowsum = 0;
    if (c == 0 && i < N_NODE) {
        M   = hx[i * 6 + 0]; E   = hx[i * 6 + 1]; I   = hx[i * 6 + 2];
        Mvv = hx[i * 6 + 3]; Evv = hx[i * 6 + 4]; Ivv = hx[i * 6 + 5];
    }
    __syncthreads();
    if (c == 0 && i < N_NODE) {
        float s = 0.0f;
        for (int j = 0; j < N_NODE; ++j) s += wn[j * N_NODE + i];
        rowsum = s;
    }

    for (int t = 0; t < NSTEP; ++t) {
        if (i < N_NODE) {
            float acc = 0.0f;
            const float* ringc = ring + c * 50 * RING;
            const float* wnc   = wn + c * 50 * N_NODE + i;
            #pragma unroll
            for (int r0 = 0; r0 < 50; ++r0) {
                unsigned e = (dpk[r0 >> 1] >> ((r0 & 1) << 4)) & 0xffffu;
                int pos = (int)(((unsigned)t + e) & 511u);
                acc = fmaf(wnc[r0 * N_NODE], ringc[r0 * RING + pos], acc);
            }
            part[c][i] = acc;
        }
        __syncthreads();
        if (c == 0 && i < N_NODE) {
            float LEd = part[0][i] + part[1][i] + part[2][i] + part[3][i];
            int b = t / 10, h = t - b * 10;
            float u  = inp     [i * 500 + h * 50 + b];
            float nz = noise_in[i * 500 + h * 50 + b];
            float rM = sigm(E - I);
            float rE = 250.0f * nz + 1000.01f * (LEd - rowsum * E) + 108.01f * sigm(135.01f * M);
            float rI = 33.76f * sigm(33.76f * M);
            float ddM = M + 1e-4f * Mvv;
            float ddE = E + 1e-4f * Evv;
            float ddI = I + 1e-4f * Ivv;
            float uu  = u + 500.0f * tanhf(rM / 500.0f);
            float ddMv = Mvv + 1e-4f * (328.25f * uu - 202.0f * Mvv - 10201.0f * M);
            float uE  = 500.0f * tanhf(rE / 500.0f);
            float ddEv = Evv + 1e-4f * (328.25f * uE - 202.0f * Evv - 10201.0f * E);
            float uI  = 500.0f * tanhf(rI / 500.0f);
            float ddIv = Ivv + 1e-4f * (1122.0f * uI - 102.0f * Ivv - 2601.0f * I);
            M   = satf(ddM);  E   = satf(ddE);  I   = satf(ddI);
            Mvv = satf(ddMv); Evv = satf(ddEv); Ivv = satf(ddIv);
            ring[i * RING + (t & 511)] = M;
            if (h == 9) {
                out[ 4400 + i * 50 + b] = E;
                out[14400 + i * 50 + b] = I;
                out[24400 + i * 50 + b] = M;
                out[34400 + i * 50 + b] = Evv;
                out[44400 + i * 50 + b] = Ivv;
                out[54400 + i * 50 + b] = Mvv;
            }
        }
        __syncthreads();
    }

    if (c == 0 && i < N_NODE) {
        out[3200 + i * 6 + 0] = M;
        out[3200 + i * 6 + 1] = E;
        out[3200 + i * 6 + 2] = I;
        out[3200 + i * 6 + 3] = Mvv;
        out[3200 + i * 6 + 4] = Evv;
        out[3200 + i * 6 + 5] = Ivv;
    }
    for (int p = tid; p < N_NODE * 500; p += 1024) {
        int ii = p / 500, dd = p - ii * 500;
        out[64400 + p] = ring[ii * RING + (499 - dd)];
    }
    __syncthreads();
    for (int p = tid; p < 64 * 50; p += 1024) {
        int o = p / 50, b = p - o * 50;
        float s = 0.0f;
        for (int n = 0; n < N_NODE; ++n)
            s += lmt[o * N_NODE + n] * (out[4400 + n * 50 + b] - out[14400 + n * 50 + b]);
        out[p] = 5.0f * s - 2.0f;
    }
}

extern "C" void kernel_launch(void* const* d_in, const int* in_sizes, int n_in,
                              void* d_out, int out_size, void* d_ws, size_t ws_size,
                              hipStream_t stream) {
    if (ws_size >= WS_NEED) {
        zero_bar<<<1, 64, 0, stream>>>((int*)((float*)d_ws + OFF_BAR));
        jansen_tb32<<<NWG, NTHR, 0, stream>>>(
            (const float*)d_in[0], (const float*)d_in[1], (const float*)d_in[2],
            (const float*)d_in[3], (const float*)d_in[4], (const float*)d_in[5],
            (const float*)d_in[6], (const int*)d_in[7],
            (float*)d_out, (float*)d_ws);
    } else {
        jansen_main<<<1, 1024, 0, stream>>>(
            (const float*)d_in[0], (const float*)d_in[1], (const float*)d_in[2],
            (const float*)d_in[3], (const float*)d_in[4], (const float*)d_in[5],
            (const float*)d_in[6], (const int*)d_in[7],
            (float*)d_out, (float*)d_ws);
    }
}

// Round 5
// 1468.335 us; speedup vs baseline: 1.8645x; 1.3622x over previous
//
#include <hip/hip_runtime.h>
#include <math.h>

#define N_NODE 200
#define RING   512
#define ROWF   545          // 512 + 32 mirror pad + 1 stagger (odd stride -> conflict-free ring writes)
#define NSTEP  500
#define TB     32
#define NB     16           // ceil(500/32); last block kmax=20
#define NWG    8
#define NTHR   256
#define JSL    25           // j-rows per WG slice
#define NEARCAP 32          // near band d < 32
#define MDEP   36           // Mrec depth (>= 33), mod-36 slots

// ---- ws layout (float element offsets) ----
#define FPBUF   (NWG * N_NODE * TB)   // 51200 floats per parity buffer
#define OFF_FP  0                     // [2][NWG][200][32] far partials (parity by block&1)
#define OFF_BAR (2 * FPBUF)           // [64] int barrier counters
#define WS_NEED ((size_t)(2 * FPBUF + 64) * 4)

// ---- static LDS layout (byte offsets into smem[]) ----
#define SM_RED   0        // double[8]
#define SM_MREC  64       // float[36*200]            -> 28864
#define SM_NOFF  28864    // u32 [32][200] TRANSPOSED -> 54464 (build only; regs in loop)
#define SM_NW    54464    // float[32][200] TRANSPOSED-> 80064 (build only; regs in loop)
#define SM_LED   80864    // float[32*200]            -> 106464
#define SM_RING  106464   // float[25*545] = 54500B   -> 160964
#define SM_TOTAL 160964
// epilogue overlays (post-loop; must stay below SM_RING until hEb flushed)
#define SM_LMT   64       // float[64*200]  -> 51264
#define SM_DIFF  51264    // float[200*50]  -> 91264

__device__ __forceinline__ float sigm(float x) {
    return 5.0f / (1.0f + expf(0.56f * (6.0f - x)));
}
__device__ __forceinline__ float satf(float x) {
    return 1000.0f * tanhf(x / 1000.0f);
}

__device__ __forceinline__ void grid_barrier(int* slot, int nwg) {
    __syncthreads();
    if (threadIdx.x == 0) {
        __threadfence();
        __hip_atomic_fetch_add(slot, 1, __ATOMIC_ACQ_REL, __HIP_MEMORY_SCOPE_AGENT);
        while (__hip_atomic_load(slot, __ATOMIC_ACQUIRE, __HIP_MEMORY_SCOPE_AGENT) < nwg) {
            __builtin_amdgcn_s_sleep(2);
        }
        __threadfence();
    }
    __syncthreads();
}

__global__ void zero_bar(int* bar) {
    if (threadIdx.x < 64) bar[threadIdx.x] = 0;
}

__global__ __launch_bounds__(NTHR, 1)
void jansen_reg(const float* __restrict__ inp, const float* __restrict__ noise_in,
                const float* __restrict__ hx,  const float* __restrict__ hE,
                const float* __restrict__ sc,  const float* __restrict__ wbb,
                const float* __restrict__ lm,  const int*   __restrict__ delays,
                float* __restrict__ out, float* __restrict__ ws)
{
    __shared__ char smem[SM_TOTAL];
    double*   red  = (double*)(smem + SM_RED);
    float*    Mrec = (float*)(smem + SM_MREC);
    unsigned* nOFF = (unsigned*)(smem + SM_NOFF);
    float*    nW   = (float*)(smem + SM_NW);
    float*    LEdS = (float*)(smem + SM_LED);
    float*    ringS= (float*)(smem + SM_RING);

    const int tid = threadIdx.x;
    const int wg  = blockIdx.x;
    const int i   = tid;            // node id (active if < 200)
    const int jlo = wg * JSL;

    float* fp  = ws + OFF_FP;
    int*   bar = (int*)(ws + OFF_BAR);

    // ---- pass A: Frobenius norm of wl (redundant per WG) ----
    double ssq = 0.0;
    for (int q = tid; q < N_NODE * N_NODE; q += NTHR) {
        int j = q / N_NODE, ii = q - j * N_NODE;
        float w1 = expf(wbb[ii * N_NODE + j]) * sc[ii * N_NODE + j];
        float w2 = expf(wbb[j * N_NODE + ii]) * sc[j * N_NODE + ii];
        float wl = log1pf(0.5f * (w1 + w2));
        ssq += (double)wl * (double)wl;
    }
    #pragma unroll
    for (int off = 32; off > 0; off >>= 1) ssq += __shfl_down(ssq, off, 64);
    if ((tid & 63) == 0) red[tid >> 6] = ssq;

    // ---- ring init: pos x holds M[-1-dd], dd=511-x; mirror [512..543] copies [0..31] ----
    for (int p = tid; p < JSL * ROWF; p += NTHR) {
        int jl = p / ROWF, x = p - jl * ROWF;
        float v = 0.0f;
        if (x < 544) {
            int dd = (x < RING) ? (511 - x) : (1023 - x);
            if (dd < 500) v = hE[(jlo + jl) * 500 + dd];
        }
        ringS[p] = v;
    }
    // ---- Mrec init: M[-q] at slot (36-q), q=1..32 -> slot s in [4,35]: hE[j][35-s] ----
    for (int p = tid; p < MDEP * N_NODE; p += NTHR) {
        int s = p / N_NODE, j = p - s * N_NODE;
        Mrec[p] = (s >= 4) ? hE[j * 500 + (35 - s)] : 0.0f;
    }
    // ---- zero-init near tables (padding entries: offset 0, weight 0) ----
    for (int p = tid; p < NEARCAP * N_NODE; p += NTHR) {
        nOFF[p] = 0u;
        nW[p]   = 0.0f;
    }
    __syncthreads();
    if (tid == 0) {
        double s = 0.0;
        #pragma unroll
        for (int r = 0; r < 8; ++r) s += red[r];
        red[0] = 1.0 / sqrt(s);
    }
    __syncthreads();
    const float inv = (float)red[0];

    // ---- pass B: near lists (transposed build), own-slice far weights, state ----
    float rowsum = 0.0f;
    float M = 0, E = 0, I = 0, Mvv = 0, Evv = 0, Ivv = 0;
    float wreg[JSL];
    int   ereg[JSL];
    #pragma unroll
    for (int jl = 0; jl < JSL; ++jl) { wreg[jl] = 0.0f; ereg[jl] = 0; }
    if (i < N_NODE) {
        int cnt = 0;
        for (int j = 0; j < N_NODE; ++j) {
            float w1 = expf(wbb[i * N_NODE + j]) * sc[i * N_NODE + j];
            float w2 = expf(wbb[j * N_NODE + i]) * sc[j * N_NODE + i];
            float w  = log1pf(0.5f * (w1 + w2)) * inv;
            int d = delays[j * N_NODE + i];
            rowsum += w;
            if (d < NEARCAP && cnt < NEARCAP) {
                nOFF[cnt * N_NODE + i] = (unsigned)((35 - d) * N_NODE + j);
                nW  [cnt * N_NODE + i] = w;
                ++cnt;
            }
        }
        #pragma unroll
        for (int jl = 0; jl < JSL; ++jl) {
            int j = jlo + jl;
            float w1 = expf(wbb[i * N_NODE + j]) * sc[i * N_NODE + j];
            float w2 = expf(wbb[j * N_NODE + i]) * sc[j * N_NODE + i];
            float w  = log1pf(0.5f * (w1 + w2)) * inv;
            int d = delays[j * N_NODE + i];
            wreg[jl] = (d < NEARCAP) ? 0.0f : w;
            ereg[jl] = 511 - d;
        }
        M   = hx[i * 6 + 0]; E   = hx[i * 6 + 1]; I   = hx[i * 6 + 2];
        Mvv = hx[i * 6 + 3]; Evv = hx[i * 6 + 4]; Ivv = hx[i * 6 + 5];
    }

    // ---- near list -> REGISTERS (loop-invariant over all 500 steps) ----
    // static indices only (rule #20); lanes >= 200 read zero-padded entries
    int   noffR[NEARCAP];
    float nwR[NEARCAP];
    {
        const int ii = (i < N_NODE) ? i : 0;
        #pragma unroll
        for (int n = 0; n < NEARCAP; ++n) {
            noffR[n] = (int)nOFF[n * N_NODE + ii];
            nwR[n]   = nW[n * N_NODE + ii];
        }
    }
    __syncthreads();

    // ---------------- main loop over 32-step blocks (serial phases) ----------------
    for (int b = 0; b < NB; ++b) {
        const int t0 = b * TB;
        float* fpb = fp + (b & 1) * FPBUF;

        float u0=0, u1=0, u2=0, n0=0, n1=0, n2=0;

        // ---- far phase: own j-slice, contiguous mirror-padded reads ----
        if (i < N_NODE) {
            float ac[TB];
            #pragma unroll
            for (int k = 0; k < TB; ++k) ac[k] = 0.0f;
            #pragma unroll
            for (int jl = 0; jl < JSL; ++jl) {
                float w  = wreg[jl];
                int   p0 = (t0 + ereg[jl]) & 511;
                const float* rb = ringS + jl * ROWF + p0;
                #pragma unroll
                for (int k = 0; k < TB; ++k)
                    ac[k] = fmaf(w, rb[k], ac[k]);
            }
            float4* fpw = (float4*)(fpb + wg * (N_NODE * TB) + i * TB);
            #pragma unroll
            for (int q = 0; q < 8; ++q)
                fpw[q] = make_float4(ac[4*q+0], ac[4*q+1], ac[4*q+2], ac[4*q+3]);

            // prime u/n depth-3 register pipeline (latency hides under barrier+gather)
            {
                int ta = t0, tb2 = t0 + 1, tc = t0 + 2;
                int ba = ta / 10,  ha = ta  - 10 * ba;
                int bbq = tb2 / 10, hb = tb2 - 10 * bbq;
                int bc = tc / 10,  hc = tc  - 10 * bc;
                u0 = inp     [i * 500 + ha * 50 + ba];
                n0 = noise_in[i * 500 + ha * 50 + ba];
                u1 = inp     [i * 500 + hb * 50 + bbq];
                n1 = noise_in[i * 500 + hb * 50 + bbq];
                u2 = inp     [i * 500 + hc * 50 + bc];
                n2 = noise_in[i * 500 + hc * 50 + bc];
            }
        }

        grid_barrier(bar + b, NWG);

        // ---- gather partials: 8 rounds of 8 float4 loads ----
        if (i < N_NODE) {
            const float* basep = fpb + i * TB;
            #pragma unroll
            for (int c = 0; c < 8; ++c) {
                float sx = 0, sy = 0, sz = 0, sw = 0;
                #pragma unroll
                for (int g = 0; g < NWG; ++g) {
                    float4 q = *(const float4*)(basep + g * (N_NODE * TB) + c * 4);
                    sx += q.x; sy += q.y; sz += q.z; sw += q.w;
                }
                LEdS[(c * 4 + 0) * N_NODE + i] = sx;
                LEdS[(c * 4 + 1) * N_NODE + i] = sy;
                LEdS[(c * 4 + 2) * N_NODE + i] = sz;
                LEdS[(c * 4 + 3) * N_NODE + i] = sw;
            }
        }
        __syncthreads();

        // ---- inner per-step phase (redundant in every WG) ----
        const int kmax = (NSTEP - t0 < TB) ? (NSTEP - t0) : TB;
        int s36 = t0 % MDEP;
        int t3  = t0 + 3;
        int bb3 = t3 / 10, hh3 = t3 - 10 * bb3;
        int bcur = t0 / 10, hcur = t0 - 10 * bcur;
        const bool ringw = (i >= jlo) && (i < jlo + JSL);
        const int  rbase = (i - jlo) * ROWF;
        for (int k = 0; k < kmax; ++k) {
            const int t = t0 + k;
            if (i < N_NODE) {
                float LEd = LEdS[k * N_NODE + i];
                const int base36 = s36 * N_NODE;
                // fixed-count, fully-unrolled near gather: 32 independent LDS reads
                #pragma unroll
                for (int n = 0; n < NEARCAP; ++n) {
                    int addr = base36 + noffR[n];
                    if (addr >= MDEP * N_NODE) addr -= MDEP * N_NODE;
                    LEd = fmaf(nwR[n], Mrec[addr], LEd);
                }
                float u  = u0;
                float nz = n0;
                float rM = sigm(E - I);
                float rE = 250.0f * nz + 1000.01f * (LEd - rowsum * E) + 108.01f * sigm(135.01f * M);
                float rI = 33.76f * sigm(33.76f * M);
                float ddM = M + 1e-4f * Mvv;
                float ddE = E + 1e-4f * Evv;
                float ddI = I + 1e-4f * Ivv;
                float uu  = u + 500.0f * tanhf(rM / 500.0f);
                float ddMv = Mvv + 1e-4f * (328.25f * uu - 202.0f * Mvv - 10201.0f * M);
                float uE  = 500.0f * tanhf(rE / 500.0f);
                float ddEv = Evv + 1e-4f * (328.25f * uE - 202.0f * Evv - 10201.0f * E);
                float uI  = 500.0f * tanhf(rI / 500.0f);
                float ddIv = Ivv + 1e-4f * (1122.0f * uI - 102.0f * Ivv - 2601.0f * I);
                M   = satf(ddM);  E   = satf(ddE);  I   = satf(ddI);
                Mvv = satf(ddMv); Evv = satf(ddEv); Ivv = satf(ddIv);
                Mrec[s36 * N_NODE + i] = M;
                if (ringw) {
                    int pt = t & 511;
                    ringS[rbase + pt] = M;
                    if (pt < 32) ringS[rbase + pt + 512] = M;
                }
                if (wg == 0 && hcur == 9) {
                    out[ 4400 + i * 50 + bcur] = E;
                    out[14400 + i * 50 + bcur] = I;
                    out[24400 + i * 50 + bcur] = M;
                    out[34400 + i * 50 + bcur] = Evv;
                    out[44400 + i * 50 + bcur] = Ivv;
                    out[54400 + i * 50 + bcur] = Mvv;
                }
                // rotate u/n pipeline; issue load for t+3
                u0 = u1; u1 = u2; n0 = n1; n1 = n2;
                if (t3 < NSTEP) {
                    u2 = inp     [i * 500 + hh3 * 50 + bb3];
                    n2 = noise_in[i * 500 + hh3 * 50 + bb3];
                }
                ++t3; ++hh3; if (hh3 == 10) { hh3 = 0; ++bb3; }
                ++hcur; if (hcur == 10) { hcur = 0; ++bcur; }
                ++s36; if (s36 == MDEP) s36 = 0;
            }
            __syncthreads();
        }
    }

    // ---------------- epilogue ----------------
    // hEb slice: rows [jlo, jlo+JSL) from LDS ring
    for (int p = tid; p < JSL * 500; p += NTHR) {
        int jl = p / 500, dd = p - jl * 500;
        out[64400 + (jlo + jl) * 500 + dd] = ringS[jl * ROWF + ((499 - dd) & 511)];
    }
    if (wg != 0) return;

    if (i < N_NODE) {
        out[3200 + i * 6 + 0] = M;
        out[3200 + i * 6 + 1] = E;
        out[3200 + i * 6 + 2] = I;
        out[3200 + i * 6 + 3] = Mvv;
        out[3200 + i * 6 + 4] = Evv;
        out[3200 + i * 6 + 5] = Ivv;
    }

    float* lmt  = (float*)(smem + SM_LMT);
    float* diff = (float*)(smem + SM_DIFF);
    __syncthreads();
    if (tid < 64) {
        float s = 0.0f;
        for (int n = 0; n < N_NODE; ++n) { float v = lm[tid * N_NODE + n]; s += v * v; }
        float ivn = 1.0f / sqrtf(s);
        for (int n = 0; n < N_NODE; ++n) lmt[tid * N_NODE + n] = lm[tid * N_NODE + n] * ivn;
    }
    __syncthreads();
    if (tid < N_NODE) {
        float s = 0.0f;
        for (int o = 0; o < 64; ++o) s += lmt[o * N_NODE + tid];
        s *= (1.0f / 64.0f);
        for (int o = 0; o < 64; ++o) lmt[o * N_NODE + tid] -= s;
    }
    __syncthreads();
    for (int p = tid; p < 10000; p += NTHR) diff[p] = out[4400 + p] - out[14400 + p];
    __syncthreads();
    for (int p = tid; p < 3200; p += NTHR) {
        int o = p / 50, bb = p - o * 50;
        float s = 0.0f;
        for (int n = 0; n < N_NODE; ++n)
            s = fmaf(lmt[o * N_NODE + n], diff[n * 50 + bb], s);
        out[p] = 5.0f * s - 2.0f;
    }
}

// ---------------- fallback: single-WG kernel ----------------
__global__ __launch_bounds__(1024, 1)
void jansen_main(const float* __restrict__ inp, const float* __restrict__ noise_in,
                 const float* __restrict__ hx,  const float* __restrict__ hE,
                 const float* __restrict__ sc,  const float* __restrict__ wbb,
                 const float* __restrict__ lm,  const int*   __restrict__ delays,
                 float* __restrict__ out, float* __restrict__ ws)
{
    const int tid = threadIdx.x;
    const int i   = tid & 255;
    const int c   = tid >> 8;

    float* ring = ws;
    float* lmt  = ws + N_NODE * RING;

    __shared__ double red[18];
    __shared__ float  part[4][N_NODE];
    __shared__ float  wn[N_NODE * N_NODE];

    double ssq = 0.0;
    for (int p = tid; p < N_NODE * N_NODE; p += 1024) {
        int r0 = p / N_NODE;
        int cc = p - r0 * N_NODE;
        float w1 = expf(wbb[p]) * sc[p];
        float w2 = expf(wbb[cc * N_NODE + r0]) * sc[cc * N_NODE + r0];
        float v  = log1pf(0.5f * (w1 + w2));
        wn[p] = v;
        ssq += (double)v * (double)v;
    }
    #pragma unroll
    for (int off = 32; off > 0; off >>= 1) ssq += __shfl_down(ssq, off, 64);
    if ((tid & 63) == 0) red[tid >> 6] = ssq;
    __syncthreads();
    if (tid == 0) {
        double s = 0.0;
        for (int k = 0; k < 16; ++k) s += red[k];
        red[16] = 1.0 / sqrt(s);
    }
    __syncthreads();
    const float inv_norm = (float)red[16];
    for (int p = tid; p < N_NODE * N_NODE; p += 1024) wn[p] *= inv_norm;

    for (int p = tid; p < N_NODE * 500; p += 1024) {
        int j = p / 500, dd = p - j * 500;
        ring[j * RING + (511 - dd)] = hE[p];
    }
    if (tid < 64) {
        float s = 0.0f;
        for (int n = 0; n < N_NODE; ++n) { float v = lm[tid * N_NODE + n]; s += v * v; }
        float inv = 1.0f / sqrtf(s);
        for (int n = 0; n < N_NODE; ++n) lmt[tid * N_NODE + n] = lm[tid * N_NODE + n] * inv;
    }
    __syncthreads();
    if (tid < N_NODE) {
        float s = 0.0f;
        for (int o = 0; o < 64; ++o) s += lmt[o * N_NODE + tid];
        s *= (1.0f / 64.0f);
        for (int o = 0; o < 64; ++o) lmt[o * N_NODE + tid] -= s;
    }

    unsigned int dpk[25];
    if (i < N_NODE) {
        #pragma unroll
        for (int r0 = 0; r0 < 25; ++r0) {
            int d0 = delays[(c * 50 + 2 * r0    ) * N_NODE + i];
            int d1 = delays[(c * 50 + 2 * r0 + 1) * N_NODE + i];
            unsigned e0 = (unsigned)((-1 - d0) & 511);
            unsigned e1 = (unsigned)((-1 - d1) & 511);
            dpk[r0] = e0 | (e1 << 16);
        }
    }

    float M = 0, E = 0, I = 0, Mvv = 0, Evv = 0, Ivv = 0, rowsum = 0;
    if (c == 0 && i < N_NODE) {
        M   = hx[i * 6 + 0]; E   = hx[i * 6 + 1]; I   = hx[i * 6 + 2];
        Mvv = hx[i * 6 + 3]; Evv = hx[i * 6 + 4]; Ivv = hx[i * 6 + 5];
    }
    __syncthreads();
    if (c == 0 && i < N_NODE) {
        float s = 0.0f;
        for (int j = 0; j < N_NODE; ++j) s += wn[j * N_NODE + i];
        rowsum = s;
    }

    for (int t = 0; t < NSTEP; ++t) {
        if (i < N_NODE) {
            float acc = 0.0f;
            const float* ringc = ring + c * 50 * RING;
            const float* wnc   = wn + c * 50 * N_NODE + i;
            #pragma unroll
            for (int r0 = 0; r0 < 50; ++r0) {
                unsigned e = (dpk[r0 >> 1] >> ((r0 & 1) << 4)) & 0xffffu;
                int pos = (int)(((unsigned)t + e) & 511u);
                acc = fmaf(wnc[r0 * N_NODE], ringc[r0 * RING + pos], acc);
            }
            part[c][i] = acc;
        }
        __syncthreads();
        if (c == 0 && i < N_NODE) {
            float LEd = part[0][i] + part[1][i] + part[2][i] + part[3][i];
            int b = t / 10, h = t - b * 10;
            float u  = inp     [i * 500 + h * 50 + b];
            float nz = noise_in[i * 500 + h * 50 + b];
            float rM = sigm(E - I);
            float rE = 250.0f * nz + 1000.01f * (LEd - rowsum * E) + 108.01f * sigm(135.01f * M);
            float rI = 33.76f * sigm(33.76f * M);
            float ddM = M + 1e-4f * Mvv;
            float ddE = E + 1e-4f * Evv;
            float ddI = I + 1e-4f * Ivv;
            float uu  = u + 500.0f * tanhf(rM / 500.0f);
            float ddMv = Mvv + 1e-4f * (328.25f * uu - 202.0f * Mvv - 10201.0f * M);
            float uE  = 500.0f * tanhf(rE / 500.0f);
            float ddEv = Evv + 1e-4f * (328.25f * uE - 202.0f * Evv - 10201.0f * E);
            float uI  = 500.0f * tanhf(rI / 500.0f);
            float ddIv = Ivv + 1e-4f * (1122.0f * uI - 102.0f * Ivv - 2601.0f * I);
            M   = satf(ddM);  E   = satf(ddE);  I   = satf(ddI);
            Mvv = satf(ddMv); Evv = satf(ddEv); Ivv = satf(ddIv);
            ring[i * RING + (t & 511)] = M;
            if (h == 9) {
                out[ 4400 + i * 50 + b] = E;
                out[14400 + i * 50 + b] = I;
                out[24400 + i * 50 + b] = M;
                out[34400 + i * 50 + b] = Evv;
                out[44400 + i * 50 + b] = Ivv;
                out[54400 + i * 50 + b] = Mvv;
            }
        }
        __syncthreads();
    }

    if (c == 0 && i < N_NODE) {
        out[3200 + i * 6 + 0] = M;
        out[3200 + i * 6 + 1] = E;
        out[3200 + i * 6 + 2] = I;
        out[3200 + i * 6 + 3] = Mvv;
        out[3200 + i * 6 + 4] = Evv;
        out[3200 + i * 6 + 5] = Ivv;
    }
    for (int p = tid; p < N_NODE * 500; p += 1024) {
        int ii = p / 500, dd = p - ii * 500;
        out[64400 + p] = ring[ii * RING + (499 - dd)];
    }
    __syncthreads();
    for (int p = tid; p < 64 * 50; p += 1024) {
        int o = p / 50, b = p - o * 50;
        float s = 0.0f;
        for (int n = 0; n < N_NODE; ++n)
            s += lmt[o * N_NODE + n] * (out[4400 + n * 50 + b] - out[14400 + n * 50 + b]);
        out[p] = 5.0f * s - 2.0f;
    }
}

extern "C" void kernel_launch(void* const* d_in, const int* in_sizes, int n_in,
                              void* d_out, int out_size, void* d_ws, size_t ws_size,
                              hipStream_t stream) {
    if (ws_size >= WS_NEED) {
        zero_bar<<<1, 64, 0, stream>>>((int*)((float*)d_ws + OFF_BAR));
        jansen_reg<<<NWG, NTHR, 0, stream>>>(
            (const float*)d_in[0], (const float*)d_in[1], (const float*)d_in[2],
            (const float*)d_in[3], (const float*)d_in[4], (const float*)d_in[5],
            (const float*)d_in[6], (const int*)d_in[7],
            (float*)d_out, (float*)d_ws);
    } else {
        jansen_main<<<1, 1024, 0, stream>>>(
            (const float*)d_in[0], (const float*)d_in[1], (const float*)d_in[2],
            (const float*)d_in[3], (const float*)d_in[4], (const float*)d_in[5],
            (const float*)d_in[6], (const int*)d_in[7],
            (float*)d_out, (float*)d_ws);
    }
}

// Round 6
// 1210.416 us; speedup vs baseline: 2.2618x; 1.2131x over previous
//
#include <hip/hip_runtime.h>
#include <math.h>

#define N_NODE 200
#define RING   512
#define ROWF   545          // 512 + 32 mirror pad + 1 stagger (odd stride -> conflict-free ring writes)
#define NSTEP  500
#define TB     32
#define NB     16           // ceil(500/32); last block kmax=20
#define NWG    8
#define NTHR   256
#define JSL    25           // j-rows per WG slice
#define NEARCAP 32          // near band d < 32
#define MDEP   36           // Mrec depth (>= 33), mod-36 slots

// ---- ws layout (float element offsets) ----
#define FPBUF   (NWG * N_NODE * TB)   // 51200 floats per parity buffer
#define OFF_FP  0                     // [2][NWG][200][32] far partials (parity by block&1)
#define OFF_BAR (2 * FPBUF)           // [64] int barrier counters
#define WS_NEED ((size_t)(2 * FPBUF + 64) * 4)

// ---- static LDS layout (byte offsets into smem[]) ----
#define SM_RED   0        // double[8]
#define SM_MREC  64       // float[36*200]            -> 28864
#define SM_US    28864    // float[32][200] u staging  (build phase: nOFF) -> 54464
#define SM_NS    54464    // float[32][200] nz staging (build phase: nW)   -> 80064
#define SM_LED   80864    // float[32*200]            -> 106464
#define SM_RING  106464   // float[25*545] = 54500B   -> 160964
#define SM_TOTAL 160964
// epilogue overlays (post-loop; must stay below SM_RING until hEb flushed)
#define SM_LMT   64       // float[64*200]  -> 51264
#define SM_DIFF  51264    // float[200*50]  -> 91264

// ---- fast transcendentals (v_exp_f32-based, ~1e-6 rel err) ----
__device__ __forceinline__ float ftanh(float x) {
    float ax = fabsf(x);
    float t  = __expf(-2.0f * ax);                       // (0,1]
    float r  = __fdividef(1.0f - t, 1.0f + t);
    return copysignf(r, x);
}
__device__ __forceinline__ float sigm(float x) {
    return __fdividef(5.0f, 1.0f + __expf(0.56f * (6.0f - x)));
}
__device__ __forceinline__ float satf(float x) {
    return 1000.0f * ftanh(x * 0.001f);
}

__device__ __forceinline__ void grid_barrier(int* slot, int nwg) {
    __syncthreads();
    if (threadIdx.x == 0) {
        __threadfence();
        __hip_atomic_fetch_add(slot, 1, __ATOMIC_ACQ_REL, __HIP_MEMORY_SCOPE_AGENT);
        while (__hip_atomic_load(slot, __ATOMIC_ACQUIRE, __HIP_MEMORY_SCOPE_AGENT) < nwg) {
            __builtin_amdgcn_s_sleep(2);
        }
        __threadfence();
    }
    __syncthreads();
}

__global__ void zero_bar(int* bar) {
    if (threadIdx.x < 64) bar[threadIdx.x] = 0;
}

__global__ __launch_bounds__(NTHR, 1)
void jansen_fast(const float* __restrict__ inp, const float* __restrict__ noise_in,
                 const float* __restrict__ hx,  const float* __restrict__ hE,
                 const float* __restrict__ sc,  const float* __restrict__ wbb,
                 const float* __restrict__ lm,  const int*   __restrict__ delays,
                 float* __restrict__ out, float* __restrict__ ws)
{
    __shared__ char smem[SM_TOTAL];
    double*   red  = (double*)(smem + SM_RED);
    float*    Mrec = (float*)(smem + SM_MREC);
    unsigned* nOFF = (unsigned*)(smem + SM_US);   // build-phase alias
    float*    nW   = (float*)(smem + SM_NS);      // build-phase alias
    float*    uS   = (float*)(smem + SM_US);      // main-loop alias
    float*    nS   = (float*)(smem + SM_NS);      // main-loop alias
    float*    LEdS = (float*)(smem + SM_LED);
    float*    ringS= (float*)(smem + SM_RING);

    const int tid = threadIdx.x;
    const int wg  = blockIdx.x;
    const int i   = tid;            // node id (active if < 200)
    const int jlo = wg * JSL;

    float* fp  = ws + OFF_FP;
    int*   bar = (int*)(ws + OFF_BAR);

    // ---- pass A: Frobenius norm of wl (redundant per WG; exact libm) ----
    double ssq = 0.0;
    for (int q = tid; q < N_NODE * N_NODE; q += NTHR) {
        int j = q / N_NODE, ii = q - j * N_NODE;
        float w1 = expf(wbb[ii * N_NODE + j]) * sc[ii * N_NODE + j];
        float w2 = expf(wbb[j * N_NODE + ii]) * sc[j * N_NODE + ii];
        float wl = log1pf(0.5f * (w1 + w2));
        ssq += (double)wl * (double)wl;
    }
    #pragma unroll
    for (int off = 32; off > 0; off >>= 1) ssq += __shfl_down(ssq, off, 64);
    if ((tid & 63) == 0) red[tid >> 6] = ssq;

    // ---- ring init: pos x holds M[-1-dd], dd=511-x; mirror [512..543] copies [0..31] ----
    for (int p = tid; p < JSL * ROWF; p += NTHR) {
        int jl = p / ROWF, x = p - jl * ROWF;
        float v = 0.0f;
        if (x < 544) {
            int dd = (x < RING) ? (511 - x) : (1023 - x);
            if (dd < 500) v = hE[(jlo + jl) * 500 + dd];
        }
        ringS[p] = v;
    }
    // ---- Mrec init: M[-q] at slot (36-q), q=1..32 -> slot s in [4,35]: hE[j][35-s] ----
    for (int p = tid; p < MDEP * N_NODE; p += NTHR) {
        int s = p / N_NODE, j = p - s * N_NODE;
        Mrec[p] = (s >= 4) ? hE[j * 500 + (35 - s)] : 0.0f;
    }
    // ---- zero-init near tables (padding entries: offset 0, weight 0) ----
    for (int p = tid; p < NEARCAP * N_NODE; p += NTHR) {
        nOFF[p] = 0u;
        nW[p]   = 0.0f;
    }
    __syncthreads();
    if (tid == 0) {
        double s = 0.0;
        #pragma unroll
        for (int r = 0; r < 8; ++r) s += red[r];
        red[0] = 1.0 / sqrt(s);
    }
    __syncthreads();
    const float inv = (float)red[0];

    // ---- pass B: near lists (transposed build), own-slice far weights, state ----
    float rowsum = 0.0f;
    float M = 0, E = 0, I = 0, Mvv = 0, Evv = 0, Ivv = 0;
    float wreg[JSL];
    int   ereg[JSL];
    #pragma unroll
    for (int jl = 0; jl < JSL; ++jl) { wreg[jl] = 0.0f; ereg[jl] = 0; }
    if (i < N_NODE) {
        int cnt = 0;
        for (int j = 0; j < N_NODE; ++j) {
            float w1 = expf(wbb[i * N_NODE + j]) * sc[i * N_NODE + j];
            float w2 = expf(wbb[j * N_NODE + i]) * sc[j * N_NODE + i];
            float w  = log1pf(0.5f * (w1 + w2)) * inv;
            int d = delays[j * N_NODE + i];
            rowsum += w;
            if (d < NEARCAP && cnt < NEARCAP) {
                nOFF[cnt * N_NODE + i] = (unsigned)((35 - d) * N_NODE + j);
                nW  [cnt * N_NODE + i] = w;
                ++cnt;
            }
        }
        #pragma unroll
        for (int jl = 0; jl < JSL; ++jl) {
            int j = jlo + jl;
            float w1 = expf(wbb[i * N_NODE + j]) * sc[i * N_NODE + j];
            float w2 = expf(wbb[j * N_NODE + i]) * sc[j * N_NODE + i];
            float w  = log1pf(0.5f * (w1 + w2)) * inv;
            int d = delays[j * N_NODE + i];
            wreg[jl] = (d < NEARCAP) ? 0.0f : w;
            ereg[jl] = 511 - d;
        }
        M   = hx[i * 6 + 0]; E   = hx[i * 6 + 1]; I   = hx[i * 6 + 2];
        Mvv = hx[i * 6 + 3]; Evv = hx[i * 6 + 4]; Ivv = hx[i * 6 + 5];
    }

    // ---- near list -> REGISTERS (loop-invariant; static indices only) ----
    int   noffR[NEARCAP];
    float nwR[NEARCAP];
    {
        const int ii = (i < N_NODE) ? i : 0;
        #pragma unroll
        for (int n = 0; n < NEARCAP; ++n) {
            noffR[n] = (int)nOFF[n * N_NODE + ii];
            nwR[n]   = nW[n * N_NODE + ii];
        }
    }
    __syncthreads();   // after this, nOFF/nW memory is reused as uS/nS

    // ---------------- main loop over 32-step blocks (serial phases) ----------------
    for (int b = 0; b < NB; ++b) {
        const int t0 = b * TB;
        float* fpb = fp + (b & 1) * FPBUF;

        // ---- far phase: own j-slice, contiguous mirror-padded reads ----
        if (i < N_NODE) {
            float ac[TB];
            #pragma unroll
            for (int k = 0; k < TB; ++k) ac[k] = 0.0f;
            #pragma unroll
            for (int jl = 0; jl < JSL; ++jl) {
                float w  = wreg[jl];
                int   p0 = (t0 + ereg[jl]) & 511;
                const float* rb = ringS + jl * ROWF + p0;
                #pragma unroll
                for (int k = 0; k < TB; ++k)
                    ac[k] = fmaf(w, rb[k], ac[k]);
            }
            float4* fpw = (float4*)(fpb + wg * (N_NODE * TB) + i * TB);
            #pragma unroll
            for (int q = 0; q < 8; ++q)
                fpw[q] = make_float4(ac[4*q+0], ac[4*q+1], ac[4*q+2], ac[4*q+3]);

            // ---- stage this block's u/noise to LDS (drain absorbed by grid barrier) ----
            #pragma unroll
            for (int k = 0; k < TB; ++k) {
                int t = t0 + k;
                float uv = 0.0f, nv = 0.0f;
                if (t < NSTEP) {
                    int bb = t / 10, h = t - 10 * bb;
                    uv = inp     [i * 500 + h * 50 + bb];
                    nv = noise_in[i * 500 + h * 50 + bb];
                }
                uS[k * N_NODE + i] = uv;
                nS[k * N_NODE + i] = nv;
            }
        }

        grid_barrier(bar + b, NWG);

        // ---- gather partials: 8 rounds of 8 float4 loads ----
        if (i < N_NODE) {
            const float* basep = fpb + i * TB;
            #pragma unroll
            for (int c = 0; c < 8; ++c) {
                float sx = 0, sy = 0, sz = 0, sw = 0;
                #pragma unroll
                for (int g = 0; g < NWG; ++g) {
                    float4 q = *(const float4*)(basep + g * (N_NODE * TB) + c * 4);
                    sx += q.x; sy += q.y; sz += q.z; sw += q.w;
                }
                LEdS[(c * 4 + 0) * N_NODE + i] = sx;
                LEdS[(c * 4 + 1) * N_NODE + i] = sy;
                LEdS[(c * 4 + 2) * N_NODE + i] = sz;
                LEdS[(c * 4 + 3) * N_NODE + i] = sw;
            }
        }
        __syncthreads();

        // ---- inner per-step phase (redundant in every WG; no global ops except wg0 out) ----
        const int kmax = (NSTEP - t0 < TB) ? (NSTEP - t0) : TB;
        int s36 = t0 % MDEP;
        int bcur = t0 / 10, hcur = t0 - 10 * bcur;
        const bool ringw = (i >= jlo) && (i < jlo + JSL);
        const int  rbase = (i - jlo) * ROWF;
        for (int k = 0; k < kmax; ++k) {
            const int t = t0 + k;
            if (i < N_NODE) {
                const int base36 = s36 * N_NODE;
                // fixed-count unrolled near gather, 4 accumulators (independent chains)
                float a0 = LEdS[k * N_NODE + i];
                float a1 = 0.0f, a2 = 0.0f, a3 = 0.0f;
                #pragma unroll
                for (int n = 0; n < NEARCAP; n += 4) {
                    int d0 = base36 + noffR[n+0]; if (d0 >= MDEP*N_NODE) d0 -= MDEP*N_NODE;
                    int d1 = base36 + noffR[n+1]; if (d1 >= MDEP*N_NODE) d1 -= MDEP*N_NODE;
                    int d2 = base36 + noffR[n+2]; if (d2 >= MDEP*N_NODE) d2 -= MDEP*N_NODE;
                    int d3 = base36 + noffR[n+3]; if (d3 >= MDEP*N_NODE) d3 -= MDEP*N_NODE;
                    a0 = fmaf(nwR[n+0], Mrec[d0], a0);
                    a1 = fmaf(nwR[n+1], Mrec[d1], a1);
                    a2 = fmaf(nwR[n+2], Mrec[d2], a2);
                    a3 = fmaf(nwR[n+3], Mrec[d3], a3);
                }
                float LEd = (a0 + a1) + (a2 + a3);
                float u  = uS[k * N_NODE + i];
                float nz = nS[k * N_NODE + i];
                float rM = sigm(E - I);
                float rE = 250.0f * nz + 1000.01f * (LEd - rowsum * E) + 108.01f * sigm(135.01f * M);
                float rI = 33.76f * sigm(33.76f * M);
                float ddM = M + 1e-4f * Mvv;
                float ddE = E + 1e-4f * Evv;
                float ddI = I + 1e-4f * Ivv;
                float uu  = u + 500.0f * ftanh(rM * 0.002f);
                float ddMv = Mvv + 1e-4f * (328.25f * uu - 202.0f * Mvv - 10201.0f * M);
                float uE  = 500.0f * ftanh(rE * 0.002f);
                float ddEv = Evv + 1e-4f * (328.25f * uE - 202.0f * Evv - 10201.0f * E);
                float uI  = 500.0f * ftanh(rI * 0.002f);
                float ddIv = Ivv + 1e-4f * (1122.0f * uI - 102.0f * Ivv - 2601.0f * I);
                M   = satf(ddM);  E   = satf(ddE);  I   = satf(ddI);
                Mvv = satf(ddMv); Evv = satf(ddEv); Ivv = satf(ddIv);
                Mrec[base36 + i] = M;
                if (ringw) {
                    int pt = t & 511;
                    ringS[rbase + pt] = M;
                    if (pt < 32) ringS[rbase + pt + 512] = M;
                }
                if (wg == 0 && hcur == 9) {
                    out[ 4400 + i * 50 + bcur] = E;
                    out[14400 + i * 50 + bcur] = I;
                    out[24400 + i * 50 + bcur] = M;
                    out[34400 + i * 50 + bcur] = Evv;
                    out[44400 + i * 50 + bcur] = Ivv;
                    out[54400 + i * 50 + bcur] = Mvv;
                }
                ++hcur; if (hcur == 10) { hcur = 0; ++bcur; }
                ++s36; if (s36 == MDEP) s36 = 0;
            }
            __syncthreads();
        }
    }

    // ---------------- epilogue ----------------
    // hEb slice: rows [jlo, jlo+JSL) from LDS ring
    for (int p = tid; p < JSL * 500; p += NTHR) {
        int jl = p / 500, dd = p - jl * 500;
        out[64400 + (jlo + jl) * 500 + dd] = ringS[jl * ROWF + ((499 - dd) & 511)];
    }
    if (wg != 0) return;

    if (i < N_NODE) {
        out[3200 + i * 6 + 0] = M;
        out[3200 + i * 6 + 1] = E;
        out[3200 + i * 6 + 2] = I;
        out[3200 + i * 6 + 3] = Mvv;
        out[3200 + i * 6 + 4] = Evv;
        out[3200 + i * 6 + 5] = Ivv;
    }

    float* lmt  = (float*)(smem + SM_LMT);
    float* diff = (float*)(smem + SM_DIFF);
    __syncthreads();
    if (tid < 64) {
        float s = 0.0f;
        for (int n = 0; n < N_NODE; ++n) { float v = lm[tid * N_NODE + n]; s += v * v; }
        float ivn = 1.0f / sqrtf(s);
        for (int n = 0; n < N_NODE; ++n) lmt[tid * N_NODE + n] = lm[tid * N_NODE + n] * ivn;
    }
    __syncthreads();
    if (tid < N_NODE) {
        float s = 0.0f;
        for (int o = 0; o < 64; ++o) s += lmt[o * N_NODE + tid];
        s *= (1.0f / 64.0f);
        for (int o = 0; o < 64; ++o) lmt[o * N_NODE + tid] -= s;
    }
    __syncthreads();
    for (int p = tid; p < 10000; p += NTHR) diff[p] = out[4400 + p] - out[14400 + p];
    __syncthreads();
    for (int p = tid; p < 3200; p += NTHR) {
        int o = p / 50, bb = p - o * 50;
        float s = 0.0f;
        for (int n = 0; n < N_NODE; ++n)
            s = fmaf(lmt[o * N_NODE + n], diff[n * 50 + bb], s);
        out[p] = 5.0f * s - 2.0f;
    }
}

// ---------------- fallback: single-WG kernel ----------------
__global__ __launch_bounds__(1024, 1)
void jansen_main(const float* __restrict__ inp, const float* __restrict__ noise_in,
                 const float* __restrict__ hx,  const float* __restrict__ hE,
                 const float* __restrict__ sc,  const float* __restrict__ wbb,
                 const float* __restrict__ lm,  const int*   __restrict__ delays,
                 float* __restrict__ out, float* __restrict__ ws)
{
    const int tid = threadIdx.x;
    const int i   = tid & 255;
    const int c   = tid >> 8;

    float* ring = ws;
    float* lmt  = ws + N_NODE * RING;

    __shared__ double red[18];
    __shared__ float  part[4][N_NODE];
    __shared__ float  wn[N_NODE * N_NODE];

    double ssq = 0.0;
    for (int p = tid; p < N_NODE * N_NODE; p += 1024) {
        int r0 = p / N_NODE;
        int cc = p - r0 * N_NODE;
        float w1 = expf(wbb[p]) * sc[p];
        float w2 = expf(wbb[cc * N_NODE + r0]) * sc[cc * N_NODE + r0];
        float v  = log1pf(0.5f * (w1 + w2));
        wn[p] = v;
        ssq += (double)v * (double)v;
    }
    #pragma unroll
    for (int off = 32; off > 0; off >>= 1) ssq += __shfl_down(ssq, off, 64);
    if ((tid & 63) == 0) red[tid >> 6] = ssq;
    __syncthreads();
    if (tid == 0) {
        double s = 0.0;
        for (int k = 0; k < 16; ++k) s += red[k];
        red[16] = 1.0 / sqrt(s);
    }
    __syncthreads();
    const float inv_norm = (float)red[16];
    for (int p = tid; p < N_NODE * N_NODE; p += 1024) wn[p] *= inv_norm;

    for (int p = tid; p < N_NODE * 500; p += 1024) {
        int j = p / 500, dd = p - j * 500;
        ring[j * RING + (511 - dd)] = hE[p];
    }
    if (tid < 64) {
        float s = 0.0f;
        for (int n = 0; n < N_NODE; ++n) { float v = lm[tid * N_NODE + n]; s += v * v; }
        float inv = 1.0f / sqrtf(s);
        for (int n = 0; n < N_NODE; ++n) lmt[tid * N_NODE + n] = lm[tid * N_NODE + n] * inv;
    }
    __syncthreads();
    if (tid < N_NODE) {
        float s = 0.0f;
        for (int o = 0; o < 64; ++o) s += lmt[o * N_NODE + tid];
        s *= (1.0f / 64.0f);
        for (int o = 0; o < 64; ++o) lmt[o * N_NODE + tid] -= s;
    }

    unsigned int dpk[25];
    if (i < N_NODE) {
        #pragma unroll
        for (int r0 = 0; r0 < 25; ++r0) {
            int d0 = delays[(c * 50 + 2 * r0    ) * N_NODE + i];
            int d1 = delays[(c * 50 + 2 * r0 + 1) * N_NODE + i];
            unsigned e0 = (unsigned)((-1 - d0) & 511);
            unsigned e1 = (unsigned)((-1 - d1) & 511);
            dpk[r0] = e0 | (e1 << 16);
        }
    }

    float M = 0, E = 0, I = 0, Mvv = 0, Evv = 0, Ivv = 0, rowsum = 0;
    if (c == 0 && i < N_NODE) {
        M   = hx[i * 6 + 0]; E   = hx[i * 6 + 1]; I   = hx[i * 6 + 2];
        Mvv = hx[i * 6 + 3]; Evv = hx[i * 6 + 4]; Ivv = hx[i * 6 + 5];
    }
    __syncthreads();
    if (c == 0 && i < N_NODE) {
        float s = 0.0f;
        for (int j = 0; j < N_NODE; ++j) s += wn[j * N_NODE + i];
        rowsum = s;
    }

    for (int t = 0; t < NSTEP; ++t) {
        if (i < N_NODE) {
            float acc = 0.0f;
            const float* ringc = ring + c * 50 * RING;
            const float* wnc   = wn + c * 50 * N_NODE + i;
            #pragma unroll
            for (int r0 = 0; r0 < 50; ++r0) {
                unsigned e = (dpk[r0 >> 1] >> ((r0 & 1) << 4)) & 0xffffu;
                int pos = (int)(((unsigned)t + e) & 511u);
                acc = fmaf(wnc[r0 * N_NODE], ringc[r0 * RING + pos], acc);
            }
            part[c][i] = acc;
        }
        __syncthreads();
        if (c == 0 && i < N_NODE) {
            float LEd = part[0][i] + part[1][i] + part[2][i] + part[3][i];
            int b = t / 10, h = t - b * 10;
            float u  = inp     [i * 500 + h * 50 + b];
            float nz = noise_in[i * 500 + h * 50 + b];
            float rM = 5.0f / (1.0f + expf(0.56f * (6.0f - (E - I))));
            float rE = 250.0f * nz + 1000.01f * (LEd - rowsum * E) + 108.01f * (5.0f / (1.0f + expf(0.56f * (6.0f - 135.01f * M))));
            float rI = 33.76f * (5.0f / (1.0f + expf(0.56f * (6.0f - 33.76f * M))));
            float ddM = M + 1e-4f * Mvv;
            float ddE = E + 1e-4f * Evv;
            float ddI = I + 1e-4f * Ivv;
            float uu  = u + 500.0f * tanhf(rM / 500.0f);
            float ddMv = Mvv + 1e-4f * (328.25f * uu - 202.0f * Mvv - 10201.0f * M);
            float uE  = 500.0f * tanhf(rE / 500.0f);
            float ddEv = Evv + 1e-4f * (328.25f * uE - 202.0f * Evv - 10201.0f * E);
            float uI  = 500.0f * tanhf(rI / 500.0f);
            float ddIv = Ivv + 1e-4f * (1122.0f * uI - 102.0f * Ivv - 2601.0f * I);
            M   = 1000.0f * tanhf(ddM / 1000.0f);
            E   = 1000.0f * tanhf(ddE / 1000.0f);
            I   = 1000.0f * tanhf(ddI / 1000.0f);
            Mvv = 1000.0f * tanhf(ddMv / 1000.0f);
            Evv = 1000.0f * tanhf(ddEv / 1000.0f);
            Ivv = 1000.0f * tanhf(ddIv / 1000.0f);
            ring[i * RING + (t & 511)] = M;
            if (h == 9) {
                out[ 4400 + i * 50 + b] = E;
                out[14400 + i * 50 + b] = I;
                out[24400 + i * 50 + b] = M;
                out[34400 + i * 50 + b] = Evv;
                out[44400 + i * 50 + b] = Ivv;
                out[54400 + i * 50 + b] = Mvv;
            }
        }
        __syncthreads();
    }

    if (c == 0 && i < N_NODE) {
        out[3200 + i * 6 + 0] = M;
        out[3200 + i * 6 + 1] = E;
        out[3200 + i * 6 + 2] = I;
        out[3200 + i * 6 + 3] = Mvv;
        out[3200 + i * 6 + 4] = Evv;
        out[3200 + i * 6 + 5] = Ivv;
    }
    for (int p = tid; p < N_NODE * 500; p += 1024) {
        int ii = p / 500, dd = p - ii * 500;
        out[64400 + p] = ring[ii * RING + (499 - dd)];
    }
    __syncthreads();
    for (int p = tid; p < 64 * 50; p += 1024) {
        int o = p / 50, b = p - o * 50;
        float s = 0.0f;
        for (int n = 0; n < N_NODE; ++n)
            s += lmt[o * N_NODE + n] * (out[4400 + n * 50 + b] - out[14400 + n * 50 + b]);
        out[p] = 5.0f * s - 2.0f;
    }
}

extern "C" void kernel_launch(void* const* d_in, const int* in_sizes, int n_in,
                              void* d_out, int out_size, void* d_ws, size_t ws_size,
                              hipStream_t stream) {
    if (ws_size >= WS_NEED) {
        zero_bar<<<1, 64, 0, stream>>>((int*)((float*)d_ws + OFF_BAR));
        jansen_fast<<<NWG, NTHR, 0, stream>>>(
            (const float*)d_in[0], (const float*)d_in[1], (const float*)d_in[2],
            (const float*)d_in[3], (const float*)d_in[4], (const float*)d_in[5],
            (const float*)d_in[6], (const int*)d_in[7],
            (float*)d_out, (float*)d_ws);
    } else {
        jansen_main<<<1, 1024, 0, stream>>>(
            (const float*)d_in[0], (const float*)d_in[1], (const float*)d_in[2],
            (const float*)d_in[3], (const float*)d_in[4], (const float*)d_in[5],
            (const float*)d_in[6], (const int*)d_in[7],
            (float*)d_out, (float*)d_ws);
    }
}